// Round 4
// baseline (607.888 us; speedup 1.0000x reference)
//
#include <hip/hip_runtime.h>
#include <hip/hip_bf16.h>

typedef __hip_bfloat16 bf16;
typedef __attribute__((ext_vector_type(8))) short short8;
typedef __attribute__((ext_vector_type(4))) float f32x4;

#define NC_ 100000
#define EC_ 1600000
#define NS_ 50000
#define ES_ 800000
#define G_  1024
#define EPS_ 1e-5f

#define CSR_WC 2000400
#define CSR_WS 1000208
#define NBC_ 98     // ceil(NC/1024)
#define NBS_ 49     // ceil(NS/1024)

#define WS_MIN_FALLBACK 39356176ull
#define WS_BIG          52163344ull

__device__ __forceinline__ float b2f(bf16 v) { return __bfloat162float(v); }

__device__ __forceinline__ unsigned short f2bfbits(float v) {
    bf16 b = __float2bfloat16(v);
    union { bf16 b; unsigned short u; } c; c.b = b; return c.u;
}

__device__ __forceinline__ void acc8(float* a, uint4 r) {
    a[0] += __uint_as_float(r.x << 16); a[1] += __uint_as_float(r.x & 0xffff0000u);
    a[2] += __uint_as_float(r.y << 16); a[3] += __uint_as_float(r.y & 0xffff0000u);
    a[4] += __uint_as_float(r.z << 16); a[5] += __uint_as_float(r.z & 0xffff0000u);
    a[6] += __uint_as_float(r.w << 16); a[7] += __uint_as_float(r.w & 0xffff0000u);
}

__global__ void DualGNN_31327491457689_kernel() {}

__global__ __launch_bounds__(256) void k_fillout(float* out, float val, int n) {
    int i = blockIdx.x * 256 + threadIdx.x;
    if (i < n) out[i] = val;
}

__global__ __launch_bounds__(256) void k_zero(int* p, int n) {
    int i = blockIdx.x * 256 + threadIdx.x;
    int stride = gridDim.x * 256;
    while (i < n) { p[i] = 0; i += stride; }
}

// ---- Pass A: per-node in-degree, both branches -------------------------
__global__ __launch_bounds__(256) void k_deg(const int* dst_c, int* deg_c,
                                             const int* dst_s, int* deg_s) {
    int t = threadIdx.x;
    const int* dst; int* deg; int E, base;
    if (blockIdx.x < 391) { dst = dst_c; deg = deg_c; E = EC_; base = blockIdx.x * 4096; }
    else { dst = dst_s; deg = deg_s; E = ES_; base = (blockIdx.x - 391) * 4096; }
    int e1 = base + 4096; if (e1 > E) e1 = E;
    for (int e = base + t; e < e1; e += 256)
        atomicAdd(&deg[dst[e]], 1);
}

// ---- Pass B1: per-1024-node block sums of padded degree ----------------
__global__ __launch_bounds__(256) void k_scanA(const int* deg_c, int* bsum_c,
                                               const int* deg_s, int* bsum_s) {
    __shared__ int wsm[4];
    const int* deg; int* bsum; int N, b;
    if ((int)blockIdx.x < NBC_) { deg = deg_c; bsum = bsum_c; N = NC_; b = blockIdx.x; }
    else { deg = deg_s; bsum = bsum_s; N = NS_; b = blockIdx.x - NBC_; }
    int t = threadIdx.x, lane = t & 63, w = t >> 6;
    int i0 = b * 1024 + t * 4;
    int d0 = 0, d1 = 0, d2 = 0, d3 = 0;
    if (i0 + 4 <= N) { int4 dd = *(const int4*)(deg + i0); d0 = dd.x; d1 = dd.y; d2 = dd.z; d3 = dd.w; }
    else {
        if (i0     < N) d0 = deg[i0];
        if (i0 + 1 < N) d1 = deg[i0 + 1];
        if (i0 + 2 < N) d2 = deg[i0 + 2];
        if (i0 + 3 < N) d3 = deg[i0 + 3];
    }
    int s = ((d0 + 3) & ~3) + ((d1 + 3) & ~3) + ((d2 + 3) & ~3) + ((d3 + 3) & ~3);
    #pragma unroll
    for (int off = 32; off > 0; off >>= 1) s += __shfl_down(s, off);
    if (lane == 0) wsm[w] = s;
    __syncthreads();
    if (t == 0) bsum[b] = wsm[0] + wsm[1] + wsm[2] + wsm[3];
}

// ---- Pass B2: scan block sums (reused small scan) -----------------------
__device__ void scan_one(const int* cnt, int* base, int* cur, int NB, int (*sc)[1024]) {
    int t = threadIdx.x;
    for (int i = t; i < 1024; i += 256) sc[0][i] = (i < NB) ? cnt[i] : 0;
    __syncthreads();
    int pin = 0;
    for (int off = 1; off < 1024; off <<= 1) {
        for (int i = t; i < 1024; i += 256) {
            int v = sc[pin][i];
            if (i >= off) v += sc[pin][i - off];
            sc[1 - pin][i] = v;
        }
        __syncthreads();
        pin ^= 1;
    }
    for (int i = t; i <= NB; i += 256) {
        int e = (i == 0) ? 0 : sc[pin][i - 1];
        base[i] = e;
        if (i < NB) cur[i] = e;
    }
    __syncthreads();
}

__global__ __launch_bounds__(256) void k_bscan(const int* cnt_c, int* base_c, int* cur_c, int NBc,
                                               const int* cnt_s, int* base_s, int* cur_s, int NBs) {
    __shared__ int sc[2][1024];
    scan_one(cnt_c, base_c, cur_c, NBc, sc);
    scan_one(cnt_s, base_s, cur_s, NBs, sc);
}

// ---- Pass B3: per-node start/cur, pad sentinels, fused u-prep ----------
__global__ __launch_bounds__(256) void k_scanC(
    const int* deg_c, const int* bbase_c, int* start_c, int* cur_c, int* csr_c,
    const float* x_c, bf16* u_c,
    const int* deg_s, const int* bbase_s, int* start_s, int* cur_s, int* csr_s,
    const float* x_s, bf16* u_s) {
    __shared__ int wsm[4];
    const int* deg; const int* bbase; int* start; int* cur; int* csr;
    const float* x; bf16* u; int N, b;
    if ((int)blockIdx.x < NBC_) {
        deg = deg_c; bbase = bbase_c; start = start_c; cur = cur_c; csr = csr_c;
        x = x_c; u = u_c; N = NC_; b = blockIdx.x;
    } else {
        deg = deg_s; bbase = bbase_s; start = start_s; cur = cur_s; csr = csr_s;
        x = x_s; u = u_s; N = NS_; b = blockIdx.x - NBC_;
    }
    int t = threadIdx.x, lane = t & 63, w = t >> 6;
    int i0 = b * 1024 + t * 4;
    int d0 = 0, d1 = 0, d2 = 0, d3 = 0;
    if (i0 + 4 <= N) { int4 dd = *(const int4*)(deg + i0); d0 = dd.x; d1 = dd.y; d2 = dd.z; d3 = dd.w; }
    else {
        if (i0     < N) d0 = deg[i0];
        if (i0 + 1 < N) d1 = deg[i0 + 1];
        if (i0 + 2 < N) d2 = deg[i0 + 2];
        if (i0 + 3 < N) d3 = deg[i0 + 3];
    }
    int p0 = (d0 + 3) & ~3, p1 = (d1 + 3) & ~3, p2 = (d2 + 3) & ~3, p3 = (d3 + 3) & ~3;
    int tsum = p0 + p1 + p2 + p3;
    int incl = tsum;
    #pragma unroll
    for (int off = 1; off < 64; off <<= 1) {
        int v = __shfl_up(incl, off);
        if (lane >= off) incl += v;
    }
    if (lane == 63) wsm[w] = incl;
    __syncthreads();
    int woff = 0;
    #pragma unroll
    for (int k = 0; k < 4; k++) if (k < w) woff += wsm[k];
    int base = bbase[b] + woff + (incl - tsum);
    int s0 = base, s1 = base + p0, s2 = base + p0 + p1, s3 = base + p0 + p1 + p2;
    if (i0 + 4 <= N) {
        *(int4*)(start + i0) = (int4){s0, s1, s2, s3};
        *(int4*)(cur + i0)   = (int4){s0, s1, s2, s3};
    } else {
        if (i0     < N) { start[i0]     = s0; cur[i0]     = s0; }
        if (i0 + 1 < N) { start[i0 + 1] = s1; cur[i0 + 1] = s1; }
        if (i0 + 2 < N) { start[i0 + 2] = s2; cur[i0 + 2] = s2; }
        if (i0 + 3 < N) { start[i0 + 3] = s3; cur[i0 + 3] = s3; }
    }
    int dd4[4] = {d0, d1, d2, d3};
    int pp4[4] = {p0, p1, p2, p3};
    int ss4[4] = {s0, s1, s2, s3};
    #pragma unroll
    for (int k = 0; k < 4; k++) {
        int i = i0 + k;
        if (i < N) {
            for (int q = dd4[k]; q < pp4[k]; q++) csr[ss4[k] + q] = N;  // pad sentinels
            if (x) {
                float di = rsqrtf((float)(dd4[k] + 1));
                union __align__(16) Pack { bf16 hh[8]; uint4 v; } pk;
                #pragma unroll
                for (int c = 0; c < 7; c++) pk.hh[c] = __float2bfloat16(x[(size_t)i * 7 + c] * di);
                pk.hh[7] = __float2bfloat16(0.f);
                ((uint4*)u)[i] = pk.v;
            }
        } else if (i == N && x) {
            ((uint4*)u)[N] = (uint4){0u, 0u, 0u, 0u};   // zero sentinel row
        }
    }
}

// ---- Pass C: scatter edges into CSR ------------------------------------
__global__ __launch_bounds__(256) void k_scatter(const int* ei_c, int* cur_c, int* csr_c,
                                                 const int* ei_s, int* cur_s, int* csr_s) {
    int t = threadIdx.x;
    const int *src, *dst; int *cur, *csr; int E, base;
    if (blockIdx.x < 391) {
        src = ei_c; dst = ei_c + EC_; cur = cur_c; csr = csr_c;
        E = EC_; base = blockIdx.x * 4096;
    } else {
        src = ei_s; dst = ei_s + ES_; cur = cur_s; csr = csr_s;
        E = ES_; base = (blockIdx.x - 391) * 4096;
    }
    int e1 = base + 4096; if (e1 > E) e1 = E;
    for (int e = base + t; e < e1; e += 256) {
        int d = dst[e];
        int s = src[e];
        int pos = atomicAdd(&cur[d], 1);
        csr[pos] = s;
    }
}

// ---- u prep (fallback path only) ---------------------------------------
__global__ __launch_bounds__(256) void k_prep7(const float* x, const int* deg,
                                               bf16* u, int N) {
    int i = blockIdx.x * 256 + threadIdx.x;
    if (i > N) return;
    union __align__(16) Pack { bf16 hh[8]; uint4 v; } p;
    if (i == N) {
        p.v = (uint4){0u, 0u, 0u, 0u};
    } else {
        float d = rsqrtf((float)(deg[i] + 1));
        for (int k = 0; k < 7; k++) p.hh[k] = __float2bfloat16(x[i * 7 + k] * d);
        p.hh[7] = __float2bfloat16(0.f);
    }
    ((uint4*)u)[i] = p.v;
}

// ---- Layer 0 gather (rank-7) + fused 7x64 GEMM, 2-lane teams, merged ---
__global__ __launch_bounds__(256) void k_gather7m(
    const bf16* u_c, const int* csr_c, const int* start_c, const int* deg_c,
    const float* W_c, const float* bias_c, bf16* h_c, float* stat_c, int N_c,
    const bf16* u_s, const int* csr_s, const int* start_s, const int* deg_s,
    const float* W_s, const float* bias_s, bf16* h_s, float* stat_s, int N_s,
    int nblk_c) {
    __shared__ float Wsm[7 * 64];
    __shared__ float agg[128][9];
    __shared__ float sm[2][4][64];
    const bf16* u; const int *csr, *start, *deg; const float *W, *bias;
    bf16* h; float* stat; int N, lb;
    if ((int)blockIdx.x < nblk_c) {
        lb = blockIdx.x; u = u_c; csr = csr_c; start = start_c; deg = deg_c;
        W = W_c; bias = bias_c; h = h_c; stat = stat_c; N = N_c;
    } else {
        lb = blockIdx.x - nblk_c; u = u_s; csr = csr_s; start = start_s; deg = deg_s;
        W = W_s; bias = bias_s; h = h_s; stat = stat_s; N = N_s;
    }
    int t = threadIdx.x, lane = t & 63, ty = t >> 6;
    int team = t >> 1, par = t & 1;
    for (int i = t; i < 448; i += 256) Wsm[i] = W[i];
    float b = bias[lane];
    float sum = 0.f, sq = 0.f;
    const uint4* up = (const uint4*)u;
    int i = lb * 128 + team;
    float a[8] = {0.f, 0.f, 0.f, 0.f, 0.f, 0.f, 0.f, 0.f};
    if (i < N) {
        int dg = deg[i], s0 = start[i];
        int adeg = (dg + 3) & ~3;
        if (par == 0) acc8(a, up[i]);            // self-loop term
        int half = ((adeg >> 1) + 3) & ~3;       // lane0: [0,half) lane1: [half,adeg)
        int jb = par ? half : 0;
        int je = par ? adeg : half;
        int j = jb;
        for (; j + 8 <= je; j += 8) {
            uint4 nA = *(const uint4*)(csr + s0 + j);
            uint4 nB = *(const uint4*)(csr + s0 + j + 4);
            uint4 r0 = up[nA.x], r1 = up[nA.y], r2 = up[nA.z], r3 = up[nA.w];
            uint4 r4 = up[nB.x], r5 = up[nB.y], r6 = up[nB.z], r7 = up[nB.w];
            acc8(a, r0); acc8(a, r1); acc8(a, r2); acc8(a, r3);
            acc8(a, r4); acc8(a, r5); acc8(a, r6); acc8(a, r7);
        }
        if (j < je) {
            uint4 nA = *(const uint4*)(csr + s0 + j);
            uint4 r0 = up[nA.x], r1 = up[nA.y], r2 = up[nA.z], r3 = up[nA.w];
            acc8(a, r0); acc8(a, r1); acc8(a, r2); acc8(a, r3);
        }
    }
    #pragma unroll
    for (int k = 0; k < 7; k++) a[k] += __shfl_xor(a[k], 1);   // combine halves
    if (i < N && par == 0) {
        float di = rsqrtf((float)(deg[i] + 1));
        #pragma unroll
        for (int k = 0; k < 7; k++) agg[team][k] = a[k] * di;
    }
    __syncthreads();
    int mbase = lb * 128 + ty * 32;
    for (int mm = 0; mm < 32; mm++) {
        int node = mbase + mm;
        if (node >= N) break;
        const float* ag = agg[ty * 32 + mm];
        float s = b;
        #pragma unroll
        for (int k = 0; k < 7; k++) s += ag[k] * Wsm[k * 64 + lane];
        h[(size_t)node * 64 + lane] = __float2bfloat16(s);
        sum += s; sq += s * s;
    }
    sm[0][ty][lane] = sum;
    sm[1][ty][lane] = sq;
    __syncthreads();
    if (ty == 0) {
        atomicAdd(&stat[lane],      sm[0][0][lane] + sm[0][1][lane] + sm[0][2][lane] + sm[0][3][lane]);
        atomicAdd(&stat[64 + lane], sm[1][0][lane] + sm[1][1][lane] + sm[1][2][lane] + sm[1][3][lane]);
    }
}

// ---- Layer 1 GEMM via MFMA, merged; y PAIR-MAJOR -----------------------
__global__ __launch_bounds__(256) void k_gemm1m(
    const bf16* h_c, const float* W_c, const float* stat_c, const float* gam_c,
    const float* bet_c, const int* deg_c, bf16* y_c, float invN_c, int N_c, int NY_c,
    const bf16* h_s, const float* W_s, const float* stat_s, const float* gam_s,
    const float* bet_s, const int* deg_s, bf16* y_s, float invN_s, int N_s, int NY_s,
    int nblk_c) {
    __shared__ short Wt[64][72];
    __shared__ float AB[128];
    const bf16* h; const float *W, *stat, *gam, *bet; const int* deg;
    bf16* y; float invN; int N, NY, lb, nb;
    if ((int)blockIdx.x < nblk_c) {
        lb = blockIdx.x; nb = nblk_c;
        h = h_c; W = W_c; stat = stat_c; gam = gam_c; bet = bet_c; deg = deg_c;
        y = y_c; invN = invN_c; N = N_c; NY = NY_c;
    } else {
        lb = blockIdx.x - nblk_c; nb = gridDim.x - nblk_c;
        h = h_s; W = W_s; stat = stat_s; gam = gam_s; bet = bet_s; deg = deg_s;
        y = y_s; invN = invN_s; N = N_s; NY = NY_s;
    }
    int t = threadIdx.x, lane = t & 63, ty = t >> 6;
    for (int i = t; i < 4096; i += 256) {
        int k = i >> 6, n = i & 63;
        Wt[n][k] = (short)f2bfbits(W[i]);
    }
    if (t < 64) {
        float mean = stat[t] * invN;
        float var = stat[64 + t] * invN - mean * mean;
        float A = gam[t] * rsqrtf(fmaxf(var, 0.f) + EPS_);
        AB[t] = A;
        AB[64 + t] = bet[t] - mean * A;
    }
    if (lb == 0 && t < 64) {     // zero sentinel row N of each pair
        int pr = t >> 4, cl = t & 15;
        y[((size_t)pr * NY + N) * 16 + cl] = __float2bfloat16(0.f);
    }
    __syncthreads();
    int quad = lane >> 4, l16 = lane & 15;
    short8 Bf[2][4];
    #pragma unroll
    for (int kt = 0; kt < 2; kt++)
        #pragma unroll
        for (int nt = 0; nt < 4; nt++) {
            int n = nt * 16 + l16, k0 = kt * 32 + quad * 8;
            Bf[kt][nt] = *(const short8*)&Wt[n][k0];
        }
    int ntile = (N + 63) >> 6;
    for (int tile = lb * 4 + ty; tile < ntile; tile += nb * 4) {
        int base = tile << 6;
        f32x4 acc[4][4];
        #pragma unroll
        for (int a = 0; a < 4; a++)
            #pragma unroll
            for (int b = 0; b < 4; b++) acc[a][b] = (f32x4){0.f, 0.f, 0.f, 0.f};
        #pragma unroll
        for (int kt = 0; kt < 2; kt++) {
            int k0 = kt * 32 + quad * 8;
            float Ak[8], Bk[8];
            #pragma unroll
            for (int j = 0; j < 8; j++) { Ak[j] = AB[k0 + j]; Bk[j] = AB[64 + k0 + j]; }
            #pragma unroll
            for (int mt = 0; mt < 4; mt++) {
                int node = base + mt * 16 + l16;     // tail overread: h padded
                uint4 raw = *(const uint4*)(h + (size_t)node * 64 + k0);
                unsigned rr[4] = {raw.x, raw.y, raw.z, raw.w};
                short8 af;
                #pragma unroll
                for (int j = 0; j < 8; j++) {
                    unsigned bits = (j & 1) ? (rr[j >> 1] & 0xffff0000u)
                                            : (rr[j >> 1] << 16);
                    float v = __uint_as_float(bits);
                    v = fmaxf(v * Ak[j] + Bk[j], 0.f);
                    af[j] = (short)f2bfbits(v);
                }
                #pragma unroll
                for (int nt = 0; nt < 4; nt++)
                    acc[mt][nt] = __builtin_amdgcn_mfma_f32_16x16x32_bf16(
                        af, Bf[kt][nt], acc[mt][nt], 0, 0, 0);
            }
        }
        #pragma unroll
        for (int mt = 0; mt < 4; mt++)
            #pragma unroll
            for (int r = 0; r < 4; r++) {
                int node = base + mt * 16 + quad * 4 + r;
                if (node < N) {
                    float dinv = rsqrtf((float)(deg[node] + 1));
                    #pragma unroll
                    for (int nt = 0; nt < 4; nt++)
                        y[((size_t)nt * NY + node) * 16 + l16] =
                            __float2bfloat16(acc[mt][nt][r] * dinv);
                }
            }
    }
}

// ---- Layer-1 gather: PAIR-MAJOR, 2-lane teams, 8-deep pipeline ---------
__global__ __launch_bounds__(256) void k_gather16p(
    const bf16* y_c, const int* csr_c, const int* start_c, const int* deg_c,
    const float* bias_c, bf16* h_c, float* stat_c, int N_c, int NY_c,
    const bf16* y_s, const int* csr_s, const int* start_s, const int* deg_s,
    const float* bias_s, bf16* h_s, float* stat_s, int N_s, int NY_s,
    int nblk_c) {
    __shared__ float sms[4][2][2][8];
    const bf16* y; const int *csr, *start, *deg; const float* bias;
    bf16* h; float* stat; int N, NY, lb, nb;
    if ((int)blockIdx.x < nblk_c) {
        lb = blockIdx.x; nb = nblk_c;
        y = y_c; csr = csr_c; start = start_c; deg = deg_c; bias = bias_c;
        h = h_c; stat = stat_c; N = N_c; NY = NY_c;
    } else {
        lb = blockIdx.x - nblk_c; nb = gridDim.x - nblk_c;
        y = y_s; csr = csr_s; start = start_s; deg = deg_s; bias = bias_s;
        h = h_s; stat = stat_s; N = N_s; NY = NY_s;
    }
    int t = threadIdx.x, lane = t & 63, ty = t >> 6;
    int team = lane >> 1, par = lane & 1;
    int pair = lb & 3;
    int grp = lb >> 2;
    int ngrp = nb >> 2;
    const uint4* yp = (const uint4*)y + (size_t)pair * NY * 2;
    uint4* hp = (uint4*)h + (size_t)pair * NY * 2;
    float b[8];
    #pragma unroll
    for (int k = 0; k < 8; k++) b[k] = bias[pair * 16 + par * 8 + k];
    float sum[8], sq[8];
    #pragma unroll
    for (int k = 0; k < 8; k++) { sum[k] = 0.f; sq[k] = 0.f; }
    for (int i = grp * 128 + ty * 32 + team; i < N; i += ngrp * 128) {
        int dg = deg[i], s0 = start[i];
        int adeg = (dg + 3) & ~3;
        float a[8];
        #pragma unroll
        for (int k = 0; k < 8; k++) a[k] = 0.f;
        acc8(a, yp[2 * i + par]);                // self-loop
        int j = 0;
        for (; j + 8 <= adeg; j += 8) {
            uint4 nA = *(const uint4*)(csr + s0 + j);
            uint4 nB = *(const uint4*)(csr + s0 + j + 4);
            uint4 q0 = yp[2 * nA.x + par];
            uint4 q1 = yp[2 * nA.y + par];
            uint4 q2 = yp[2 * nA.z + par];
            uint4 q3 = yp[2 * nA.w + par];
            uint4 q4 = yp[2 * nB.x + par];
            uint4 q5 = yp[2 * nB.y + par];
            uint4 q6 = yp[2 * nB.z + par];
            uint4 q7 = yp[2 * nB.w + par];
            acc8(a, q0); acc8(a, q1); acc8(a, q2); acc8(a, q3);
            acc8(a, q4); acc8(a, q5); acc8(a, q6); acc8(a, q7);
        }
        if (j < adeg) {
            uint4 nA = *(const uint4*)(csr + s0 + j);
            uint4 q0 = yp[2 * nA.x + par];
            uint4 q1 = yp[2 * nA.y + par];
            uint4 q2 = yp[2 * nA.z + par];
            uint4 q3 = yp[2 * nA.w + par];
            acc8(a, q0); acc8(a, q1); acc8(a, q2); acc8(a, q3);
        }
        float di = rsqrtf((float)(dg + 1));
        union __align__(16) Pack { bf16 hh[8]; uint4 v; } p;
        #pragma unroll
        for (int k = 0; k < 8; k++) {
            float v = a[k] * di + b[k];
            p.hh[k] = __float2bfloat16(v);
            sum[k] += v; sq[k] += v * v;
        }
        hp[2 * i + par] = p.v;
    }
    #pragma unroll
    for (int k = 0; k < 8; k++) {
        float s1 = sum[k], s2 = sq[k];
        s1 += __shfl_down(s1, 32); s2 += __shfl_down(s2, 32);
        s1 += __shfl_down(s1, 16); s2 += __shfl_down(s2, 16);
        s1 += __shfl_down(s1, 8);  s2 += __shfl_down(s2, 8);
        s1 += __shfl_down(s1, 4);  s2 += __shfl_down(s2, 4);
        s1 += __shfl_down(s1, 2);  s2 += __shfl_down(s2, 2);
        if (lane < 2) { sms[ty][lane][0][k] = s1; sms[ty][lane][1][k] = s2; }
    }
    __syncthreads();
    if (t < 16) {
        int pp = t >> 3, k = t & 7;
        atomicAdd(&stat[pair * 16 + pp * 8 + k],
                  sms[0][pp][0][k] + sms[1][pp][0][k] + sms[2][pp][0][k] + sms[3][pp][0][k]);
    } else if (t >= 64 && t < 80) {
        int q = t - 64, pp = q >> 3, k = q & 7;
        atomicAdd(&stat[64 + pair * 16 + pp * 8 + k],
                  sms[0][pp][1][k] + sms[1][pp][1][k] + sms[2][pp][1][k] + sms[3][pp][1][k]);
    }
}

// ---- Pool merged: BN1+ReLU fused; reads h PAIR-MAJOR -------------------
__global__ __launch_bounds__(256) void k_poolm(
    const bf16* h_c, const float* stat_c, const float* gam_c, const float* bet_c,
    const int* batch_c, float* pooled_c, float* cnt_c, float invN_c, int N_c, int NY_c,
    const bf16* h_s, const float* stat_s, const float* gam_s, const float* bet_s,
    const int* batch_s, float* pooled_s, float* cnt_s, float invN_s, int N_s, int NY_s,
    int nblk_c) {
    const bf16* h; const float *stat, *gam, *bet; const int* batch;
    float *pooled, *cnt; float invN; int N, NY, lb, nb;
    if ((int)blockIdx.x < nblk_c) {
        lb = blockIdx.x; nb = nblk_c;
        h = h_c; stat = stat_c; gam = gam_c; bet = bet_c; batch = batch_c;
        pooled = pooled_c; cnt = cnt_c; invN = invN_c; N = N_c; NY = NY_c;
    } else {
        lb = blockIdx.x - nblk_c; nb = gridDim.x - nblk_c;
        h = h_s; stat = stat_s; gam = gam_s; bet = bet_s; batch = batch_s;
        pooled = pooled_s; cnt = cnt_s; invN = invN_s; N = N_s; NY = NY_s;
    }
    int t = threadIdx.x;
    int lane = t & 63;
    float mean = stat[lane] * invN;
    float var = stat[64 + lane] * invN - mean * mean;
    float A = gam[lane] * rsqrtf(fmaxf(var, 0.f) + EPS_);
    float B = bet[lane] - mean * A;
    size_t pbase = (size_t)(lane >> 4) * NY * 16 + (lane & 15);
    int w = (lb * 256 + t) >> 6;
    int nw = nb * 4;
    int chunk = (N + nw - 1) / nw;
    int i0 = w * chunk;
    int i1 = i0 + chunk;
    if (i1 > N) i1 = N;
    if (i0 >= N) return;
    int curg = batch[i0];
    float acc = 0.f, c = 0.f;
    for (int i = i0; i < i1; i++) {
        int g = batch[i];
        if (g != curg) {
            atomicAdd(&pooled[(size_t)curg * 64 + lane], acc);
            if (lane == 0) atomicAdd(&cnt[curg], c);
            curg = g; acc = 0.f; c = 0.f;
        }
        acc += fmaxf(b2f(h[pbase + (size_t)i * 16]) * A + B, 0.f);
        c += 1.f;
    }
    atomicAdd(&pooled[(size_t)curg * 64 + lane], acc);
    if (lane == 0) atomicAdd(&cnt[curg], c);
}

// ---- Head --------------------------------------------------------------
__global__ __launch_bounds__(64) void k_head(const float* pooled_c, const float* cnt_c,
                                             const float* pooled_s, const float* cnt_s,
                                             const float* Wf1, const float* bf1_,
                                             const float* Wf2, const float* bf2_,
                                             float* out) {
    __shared__ float W1sm[128 * 64];
    __shared__ float W2sm[128];
    int t = threadIdx.x;
    for (int i = t; i < 128 * 64; i += 64) W1sm[i] = Wf1[i];
    for (int i = t; i < 128; i += 64) W2sm[i] = Wf2[i];
    __syncthreads();
    float bb1 = bf1_[t];
    float b20 = bf2_[0];
    float b21 = bf2_[1];
    for (int g = blockIdx.x; g < G_; g += gridDim.x) {
        float ic = 1.f / fmaxf(cnt_c[g], 1.f);
        float is = 1.f / fmaxf(cnt_s[g], 1.f);
        float hc = pooled_c[(size_t)g * 64 + t] * ic;
        float hs = pooled_s[(size_t)g * 64 + t] * is;
        float s = bb1;
        for (int k = 0; k < 64; k++) s += __shfl(hc, k) * W1sm[k * 64 + t];
        for (int k = 0; k < 64; k++) s += __shfl(hs, k) * W1sm[(64 + k) * 64 + t];
        s = fmaxf(s, 0.f);
        float p0 = s * W2sm[t * 2 + 0];
        float p1 = s * W2sm[t * 2 + 1];
        for (int off = 32; off > 0; off >>= 1) {
            p0 += __shfl_down(p0, off);
            p1 += __shfl_down(p1, off);
        }
        if (t == 0) {
            out[g * 2 + 0] = p0 + b20;
            out[g * 2 + 1] = p1 + b21;
        }
    }
}

extern "C" void kernel_launch(void* const* d_in, const int* in_sizes, int n_in,
                              void* d_out, int out_size, void* d_ws, size_t ws_size,
                              hipStream_t stream) {
    float* out = (float*)d_out;

    if (n_in != 26 || in_sizes[0] != NC_ * 7 || in_sizes[1] != 2 * EC_ ||
        in_sizes[2] != NC_ || in_sizes[3] != NS_ * 7 || in_sizes[4] != 2 * ES_ ||
        in_sizes[5] != NS_ || out_size != G_ * 2) {
        k_fillout<<<(out_size + 255) / 256, 256, 0, stream>>>(out, 7777.0f, out_size);
        return;
    }
    if (ws_size < (size_t)WS_MIN_FALLBACK) {
        k_fillout<<<(out_size + 255) / 256, 256, 0, stream>>>(
            out, 1000.0f + (float)(ws_size >> 20), out_size);
        return;
    }
    const bool big = (ws_size >= (size_t)WS_BIG);

    const float* x_c     = (const float*)d_in[0];
    const int*   ei_c    = (const int*)d_in[1];
    const int*   batch_c = (const int*)d_in[2];
    const float* x_s     = (const float*)d_in[3];
    const int*   ei_s    = (const int*)d_in[4];
    const int*   batch_s = (const int*)d_in[5];
    const float* Wc0  = (const float*)d_in[6];
    const float* bc0  = (const float*)d_in[7];
    const float* gc0  = (const float*)d_in[8];
    const float* bec0 = (const float*)d_in[9];
    const float* Wc1  = (const float*)d_in[10];
    const float* bc1  = (const float*)d_in[11];
    const float* gc1  = (const float*)d_in[12];
    const float* bec1 = (const float*)d_in[13];
    const float* Ws0  = (const float*)d_in[14];
    const float* bs0  = (const float*)d_in[15];
    const float* gs0  = (const float*)d_in[16];
    const float* bes0 = (const float*)d_in[17];
    const float* Ws1  = (const float*)d_in[18];
    const float* bs1  = (const float*)d_in[19];
    const float* gs1  = (const float*)d_in[20];
    const float* bes1 = (const float*)d_in[21];
    const float* Wf1  = (const float*)d_in[22];
    const float* bf1_ = (const float*)d_in[23];
    const float* Wf2  = (const float*)d_in[24];
    const float* bf2_ = (const float*)d_in[25];

    const int NYC = NC_ + 8;
    const int NYS = NS_ + 8;

    // ---- workspace layout: bf16 buffers FIRST (aligned rows) -----------
    int* wsw = (int*)d_ws;
    size_t off = big ? (size_t)(3201024 + 3200256 + 1601536 + 1600256)
                     : (size_t)(3201024 + 3200256);
    // zeroed region (contiguous): stats, pooled, cnt, deg
    float* stats_c  = (float*)(wsw + off); off += 256;
    float* stats_s  = (float*)(wsw + off); off += 256;
    float* pooled_c = (float*)(wsw + off); off += (size_t)G_ * 64;
    float* pooled_s = (float*)(wsw + off); off += (size_t)G_ * 64;
    float* cnt_c    = (float*)(wsw + off); off += G_;
    float* cnt_s    = (float*)(wsw + off); off += G_;
    int*   deg_c    = wsw + off; off += NC_;
    int*   deg_s    = wsw + off; off += NS_;
    const int zero_words = 256 + 256 + G_ * 64 * 2 + G_ * 2 + NC_ + NS_;
    // scan scratch (written fully each launch)
    int*   bsum_c   = wsw + off; off += 100;
    int*   bbase2_c = wsw + off; off += 100;
    int*   bcur2_c  = wsw + off; off += 100;
    int*   bsum_s   = wsw + off; off += 52;
    int*   bbase2_s = wsw + off; off += 52;
    int*   bcur2_s  = wsw + off; off += 52;
    int*   start_c  = wsw + off; off += NC_;
    int*   start_s  = wsw + off; off += NS_;
    int*   csr_c    = wsw + off; off += CSR_WC;
    int*   csr_s    = wsw + off; off += CSR_WS;

    k_zero<<<512, 256, 0, stream>>>((int*)stats_c, zero_words);
    k_deg<<<587, 256, 0, stream>>>(ei_c + EC_, deg_c, ei_s + ES_, deg_s);
    k_scanA<<<NBC_ + NBS_, 256, 0, stream>>>(deg_c, bsum_c, deg_s, bsum_s);
    k_bscan<<<1, 256, 0, stream>>>(bsum_c, bbase2_c, bcur2_c, NBC_,
                                   bsum_s, bbase2_s, bcur2_s, NBS_);

    if (big) {
        bf16* h_c = (bf16*)wsw;                                  // 3201024 words
        bf16* y_c = (bf16*)(wsw + 3201024);                      // 3200256 words
        bf16* h_s = (bf16*)(wsw + 3201024 + 3200256);            // 1601536 words
        bf16* y_s = (bf16*)(wsw + 3201024 + 3200256 + 1601536);  // 1600256 words
        int*  cur_c = (int*)h_c;            // dead before gather7m writes h_c
        int*  cur_s = (int*)h_c + NC_;
        bf16* u_c = y_c;                    // dead before gemm1m writes y_c
        bf16* u_s = y_s;

        k_scanC<<<NBC_ + NBS_, 256, 0, stream>>>(
            deg_c, bbase2_c, start_c, cur_c, csr_c, x_c, u_c,
            deg_s, bbase2_s, start_s, cur_s, csr_s, x_s, u_s);
        k_scatter<<<587, 256, 0, stream>>>(ei_c, cur_c, csr_c, ei_s, cur_s, csr_s);
        k_gather7m<<<782 + 391, 256, 0, stream>>>(
            u_c, csr_c, start_c, deg_c, Wc0, bc0, h_c, stats_c, NC_,
            u_s, csr_s, start_s, deg_s, Ws0, bs0, h_s, stats_s, NS_, 782);
        k_gemm1m<<<768, 256, 0, stream>>>(
            h_c, Wc1, stats_c, gc0, bec0, deg_c, y_c, 1.0f / NC_, NC_, NYC,
            h_s, Ws1, stats_s, gs0, bes0, deg_s, y_s, 1.0f / NS_, NS_, NYS, 512);
        k_gather16p<<<3128 + 1564, 256, 0, stream>>>(
            y_c, csr_c, start_c, deg_c, bc1, h_c, stats_c + 128, NC_, NYC,
            y_s, csr_s, start_s, deg_s, bs1, h_s, stats_s + 128, NS_, NYS, 3128);
        k_poolm<<<384, 256, 0, stream>>>(
            h_c, stats_c + 128, gc1, bec1, batch_c, pooled_c, cnt_c, 1.0f / NC_, NC_, NYC,
            h_s, stats_s + 128, gs1, bes1, batch_s, pooled_s, cnt_s, 1.0f / NS_, NS_, NYS, 256);
    } else {
        bf16* hbuf = (bf16*)wsw;
        bf16* ybuf = (bf16*)(wsw + 3201024);
        int*  cur_c = (int*)hbuf;
        int*  cur_s = (int*)hbuf + NC_;
        bf16* ub = ybuf;

        k_scanC<<<NBC_ + NBS_, 256, 0, stream>>>(
            deg_c, bbase2_c, start_c, cur_c, csr_c, x_c, ub,
            deg_s, bbase2_s, start_s, cur_s, csr_s, (const float*)0, (bf16*)0);
        k_scatter<<<587, 256, 0, stream>>>(ei_c, cur_c, csr_c, ei_s, cur_s, csr_s);
        // chromo
        k_gather7m<<<782, 256, 0, stream>>>(
            ub, csr_c, start_c, deg_c, Wc0, bc0, hbuf, stats_c, NC_,
            ub, csr_c, start_c, deg_c, Wc0, bc0, hbuf, stats_c, NC_, 782);
        k_gemm1m<<<512, 256, 0, stream>>>(
            hbuf, Wc1, stats_c, gc0, bec0, deg_c, ybuf, 1.0f / NC_, NC_, NYC,
            hbuf, Wc1, stats_c, gc0, bec0, deg_c, ybuf, 1.0f / NC_, NC_, NYC, 512);
        k_gather16p<<<3128, 256, 0, stream>>>(
            ybuf, csr_c, start_c, deg_c, bc1, hbuf, stats_c + 128, NC_, NYC,
            ybuf, csr_c, start_c, deg_c, bc1, hbuf, stats_c + 128, NC_, NYC, 3128);
        k_poolm<<<256, 256, 0, stream>>>(
            hbuf, stats_c + 128, gc1, bec1, batch_c, pooled_c, cnt_c, 1.0f / NC_, NC_, NYC,
            hbuf, stats_c + 128, gc1, bec1, batch_c, pooled_c, cnt_c, 1.0f / NC_, NC_, NYC, 256);
        // solvent
        k_prep7<<<(NS_ + 256) / 256, 256, 0, stream>>>(x_s, deg_s, ub, NS_);
        k_gather7m<<<391, 256, 0, stream>>>(
            ub, csr_s, start_s, deg_s, Ws0, bs0, hbuf, stats_s, NS_,
            ub, csr_s, start_s, deg_s, Ws0, bs0, hbuf, stats_s, NS_, 391);
        k_gemm1m<<<256, 256, 0, stream>>>(
            hbuf, Ws1, stats_s, gs0, bes0, deg_s, ybuf, 1.0f / NS_, NS_, NYS,
            hbuf, Ws1, stats_s, gs0, bes0, deg_s, ybuf, 1.0f / NS_, NS_, NYS, 256);
        k_gather16p<<<1564, 256, 0, stream>>>(
            ybuf, csr_s, start_s, deg_s, bs1, hbuf, stats_s + 128, NS_, NYS,
            ybuf, csr_s, start_s, deg_s, bs1, hbuf, stats_s + 128, NS_, NYS, 1564);
        k_poolm<<<256, 256, 0, stream>>>(
            hbuf, stats_s + 128, gs1, bes1, batch_s, pooled_s, cnt_s, 1.0f / NS_, NS_, NYS,
            hbuf, stats_s + 128, gs1, bes1, batch_s, pooled_s, cnt_s, 1.0f / NS_, NS_, NYS, 256);
    }

    k_head<<<128, 64, 0, stream>>>(pooled_c, cnt_c, pooled_s, cnt_s, Wf1, bf1_, Wf2, bf2_, out);
}

// Round 5
// 441.894 us; speedup vs baseline: 1.3756x; 1.3756x over previous
//
#include <hip/hip_runtime.h>
#include <hip/hip_bf16.h>

typedef __hip_bfloat16 bf16;
typedef __attribute__((ext_vector_type(8))) short short8;
typedef __attribute__((ext_vector_type(4))) float f32x4;

#define NC_ 100000
#define EC_ 1600000
#define NS_ 50000
#define ES_ 800000
#define G_  1024
#define EPS_ 1e-5f

#define NB_C 782
#define NB_S 391
#define NBMAX 782
#define KSL 16
#define CSR_WC 2000400    // EC_ + 512*NB_C + 16
#define CSR_WS 1000208    // ES_ + 512*NB_S + 16

#define WS_MIN_FALLBACK 39356176ull
#define WS_BIG          52163344ull

__device__ __forceinline__ float b2f(bf16 v) { return __bfloat162float(v); }

__device__ __forceinline__ unsigned short f2bfbits(float v) {
    bf16 b = __float2bfloat16(v);
    union { bf16 b; unsigned short u; } c; c.b = b; return c.u;
}

__device__ __forceinline__ void acc8(float* a, uint4 r) {
    a[0] += __uint_as_float(r.x << 16); a[1] += __uint_as_float(r.x & 0xffff0000u);
    a[2] += __uint_as_float(r.y << 16); a[3] += __uint_as_float(r.y & 0xffff0000u);
    a[4] += __uint_as_float(r.z << 16); a[5] += __uint_as_float(r.z & 0xffff0000u);
    a[6] += __uint_as_float(r.w << 16); a[7] += __uint_as_float(r.w & 0xffff0000u);
}

__global__ void DualGNN_31327491457689_kernel() {}

__global__ __launch_bounds__(256) void k_fillout(float* out, float val, int n) {
    int i = blockIdx.x * 256 + threadIdx.x;
    if (i < n) out[i] = val;
}

__global__ __launch_bounds__(256) void k_zero(int* p, int n) {
    int i = blockIdx.x * 256 + threadIdx.x;
    int stride = gridDim.x * 256;
    while (i < n) { p[i] = 0; i += stride; }
}

// ---- Phase A: bucket histograms, both branches (96 blocks: amortize
// per-block zero/flush overhead over 4x more edges) ----------------------
__global__ __launch_bounds__(256) void k_bhist2(const int* dst_c, int* bcnt_c,
                                                const int* dst_s, int* bcnt_s) {
    __shared__ int h[NBMAX];
    int t = threadIdx.x;
    const int* dst; int* bcnt; int E, NB, b0, nb;
    if (blockIdx.x < 64) { dst = dst_c; bcnt = bcnt_c; E = EC_; NB = NB_C; b0 = blockIdx.x; nb = 64; }
    else { dst = dst_s; bcnt = bcnt_s; E = ES_; NB = NB_S; b0 = blockIdx.x - 64; nb = 32; }
    for (int i = t; i < NB; i += 256) h[i] = 0;
    __syncthreads();
    for (int e = b0 * 256 + t; e < E; e += nb * 256)
        atomicAdd(&h[dst[e] >> 7], 1);
    __syncthreads();
    for (int i = t; i < NB; i += 256) {
        int v = h[i];
        if (v) atomicAdd(&bcnt[i], v);
    }
}

// ---- Phase B: scan bucket counts ---------------------------------------
__device__ void scan_one(const int* cnt, int* base, int* cur, int NB, int (*sc)[1024]) {
    int t = threadIdx.x;
    for (int i = t; i < 1024; i += 256) sc[0][i] = (i < NB) ? cnt[i] : 0;
    __syncthreads();
    int pin = 0;
    for (int off = 1; off < 1024; off <<= 1) {
        for (int i = t; i < 1024; i += 256) {
            int v = sc[pin][i];
            if (i >= off) v += sc[pin][i - off];
            sc[1 - pin][i] = v;
        }
        __syncthreads();
        pin ^= 1;
    }
    for (int i = t; i <= NB; i += 256) {
        int e = (i == 0) ? 0 : sc[pin][i - 1];
        base[i] = e;
        if (i < NB) cur[i] = e;
    }
    __syncthreads();
}

__global__ __launch_bounds__(256) void k_bscan(const int* cnt_c, int* base_c, int* cur_c, int NBc,
                                               const int* cnt_s, int* base_s, int* cur_s, int NBs) {
    __shared__ int sc[2][1024];
    scan_one(cnt_c, base_c, cur_c, NBc, sc);
    scan_one(cnt_s, base_s, cur_s, NBs, sc);
}

// ---- Phase C: bin packed edges (294 blocks x 8192 edges: longer
// per-bucket flush runs -> ~2x less scattered-write amplification) -------
__global__ __launch_bounds__(256) void k_bin2(const int* ei_c, int* bcur_c, int* ebuf_c,
                                              const int* ei_s, int* bcur_s, int* ebuf_s) {
    __shared__ int cnt[NBMAX];
    __shared__ int slot[NBMAX * KSL];
    int t = threadIdx.x;
    const int *src, *dst; int *bcur, *ebuf; int E, NB; int base;
    if (blockIdx.x < 196) {
        src = ei_c; dst = ei_c + EC_; bcur = bcur_c; ebuf = ebuf_c;
        E = EC_; NB = NB_C; base = blockIdx.x * 8192;
    } else {
        src = ei_s; dst = ei_s + ES_; bcur = bcur_s; ebuf = ebuf_s;
        E = ES_; NB = NB_S; base = (blockIdx.x - 196) * 8192;
    }
    if (base >= E) return;
    for (int i = t; i < NB; i += 256) cnt[i] = 0;
    __syncthreads();
    int e1 = base + 8192;
    if (e1 > E) e1 = E;
    for (int e = base + t; e < e1; e += 256) {
        int d = dst[e];
        int p = ((d & 127) << 24) | src[e];
        int b = d >> 7;
        int sl = atomicAdd(&cnt[b], 1);
        if (sl < KSL) slot[b * KSL + sl] = p;
        else { int gp = atomicAdd(&bcur[b], 1); ebuf[gp] = p; }
    }
    __syncthreads();
    for (int b = t; b < NB; b += 256) {
        int c = cnt[b];
        if (c > KSL) c = KSL;
        if (c > 0) {
            int gp = atomicAdd(&bcur[b], c);
            for (int k = 0; k < c; k++) ebuf[gp + k] = slot[b * KSL + k];
        }
    }
}

// ---- Phase D: per-bucket build + u prep (both branches) ----------------
__global__ __launch_bounds__(256) void k_build2(const int* bbase_c, const int* ebuf_c,
                                                const float* x_c, bf16* u_c,
                                                int* deg_c, int* start_c, int* csr_c,
                                                const int* bbase_s, const int* ebuf_s,
                                                const float* x_s, bf16* u_s,
                                                int* deg_s, int* start_s, int* csr_s) {
    __shared__ int lcnt[128], lofs[128], lcur[128];
    int t = threadIdx.x;
    const int* bbase; const int* ebuf; const float* x; bf16* u;
    int* deg; int* start; int* csr; int N, b;
    if (blockIdx.x < NB_C) {
        b = blockIdx.x; bbase = bbase_c; ebuf = ebuf_c; x = x_c; u = u_c;
        deg = deg_c; start = start_c; csr = csr_c; N = NC_;
    } else {
        b = blockIdx.x - NB_C; bbase = bbase_s; ebuf = ebuf_s; x = x_s; u = u_s;
        deg = deg_s; start = start_s; csr = csr_s; N = NS_;
    }
    int e0 = bbase[b], e1 = bbase[b + 1];
    int cb = ((e0 + 512 * b) + 3) & ~3;
    int n0 = b << 7;
    if (t < 128) lcnt[t] = 0;
    __syncthreads();
    for (int e = e0 + t; e < e1; e += 256)
        atomicAdd(&lcnt[((unsigned)ebuf[e]) >> 24], 1);
    __syncthreads();
    if (t < 64) {
        int c0 = lcnt[2 * t], c1 = lcnt[2 * t + 1];
        int v0 = (c0 + 3) & ~3, v1 = (c1 + 3) & ~3;
        int s = v0 + v1, incl = s;
        for (int off = 1; off < 64; off <<= 1) {
            int uu = __shfl_up(incl, off);
            if (t >= off) incl += uu;
        }
        int excl = incl - s;
        lofs[2 * t] = excl;
        lofs[2 * t + 1] = excl + v0;
    }
    __syncthreads();
    if (t < 128) {
        int node = n0 + t;
        if (node < N) {
            deg[node] = lcnt[t];
            start[node] = cb + lofs[t];
            if (x) {
                float d = rsqrtf((float)(lcnt[t] + 1));
                union __align__(16) Pack { bf16 hh[8]; uint4 v; } p;
                for (int k = 0; k < 7; k++) p.hh[k] = __float2bfloat16(x[node * 7 + k] * d);
                p.hh[7] = __float2bfloat16(0.f);
                ((uint4*)u)[node] = p.v;
            }
        }
        lcur[t] = lofs[t];
    }
    __syncthreads();
    if (t < 128) {
        int c = lcnt[t], al = (c + 3) & ~3;
        for (int k = c; k < al; k++) csr[cb + lofs[t] + k] = N;
    }
    for (int e = e0 + t; e < e1; e += 256) {
        unsigned p = (unsigned)ebuf[e];
        int dl = p >> 24;
        int pos = atomicAdd(&lcur[dl], 1);
        csr[cb + pos] = (int)(p & 0xFFFFFF);
    }
    if (b == 0 && t < 4 && u && x) ((int*)u)[N * 4 + t] = 0;   // zero sentinel row
}

// ---- u prep (fallback path only) ---------------------------------------
__global__ __launch_bounds__(256) void k_prep7(const float* x, const int* deg,
                                               bf16* u, int N) {
    int i = blockIdx.x * 256 + threadIdx.x;
    if (i > N) return;
    union __align__(16) Pack { bf16 hh[8]; uint4 v; } p;
    if (i == N) {
        p.v = (uint4){0u, 0u, 0u, 0u};
    } else {
        float d = rsqrtf((float)(deg[i] + 1));
        for (int k = 0; k < 7; k++) p.hh[k] = __float2bfloat16(x[i * 7 + k] * d);
        p.hh[7] = __float2bfloat16(0.f);
    }
    ((uint4*)u)[i] = p.v;
}

// ---- Layer 0 gather (rank-7) + fused 7x64 GEMM, 2-lane teams, merged ---
__global__ __launch_bounds__(256) void k_gather7m(
    const bf16* u_c, const int* csr_c, const int* start_c, const int* deg_c,
    const float* W_c, const float* bias_c, bf16* h_c, float* stat_c, int N_c,
    const bf16* u_s, const int* csr_s, const int* start_s, const int* deg_s,
    const float* W_s, const float* bias_s, bf16* h_s, float* stat_s, int N_s,
    int nblk_c) {
    __shared__ float Wsm[7 * 64];
    __shared__ float agg[128][9];
    __shared__ float sm[2][4][64];
    __shared__ int scsr[4096];
    const bf16* u; const int *csr, *start, *deg; const float *W, *bias;
    bf16* h; float* stat; int N, lb;
    if ((int)blockIdx.x < nblk_c) {
        lb = blockIdx.x; u = u_c; csr = csr_c; start = start_c; deg = deg_c;
        W = W_c; bias = bias_c; h = h_c; stat = stat_c; N = N_c;
    } else {
        lb = blockIdx.x - nblk_c; u = u_s; csr = csr_s; start = start_s; deg = deg_s;
        W = W_s; bias = bias_s; h = h_s; stat = stat_s; N = N_s;
    }
    int t = threadIdx.x, lane = t & 63, ty = t >> 6;
    int team = t >> 1, par = t & 1;
    for (int i = t; i < 448; i += 256) Wsm[i] = W[i];
    float b = bias[lane];
    float sum = 0.f, sq = 0.f;
    const uint4* up = (const uint4*)u;
    // stage this bucket's contiguous csr span
    int n0 = lb * 128;
    int last = (n0 + 127 < N) ? n0 + 127 : N - 1;
    int sbeg = start[n0];
    int span = start[last] + ((deg[last] + 3) & ~3) - sbeg;
    bool uselds = (span <= 4096);
    if (uselds) {
        for (int w = t * 4; w < span; w += 1024)
            *(int4*)&scsr[w] = *(const int4*)(csr + sbeg + w);
    }
    __syncthreads();
    int i = n0 + team;
    float a[8] = {0.f, 0.f, 0.f, 0.f, 0.f, 0.f, 0.f, 0.f};
    if (i < N) {
        int dg = deg[i], s0 = start[i];
        int adeg = (dg + 3) & ~3;
        if (par == 0) acc8(a, up[i]);            // self-loop term
        int half = ((adeg >> 1) + 3) & ~3;       // lane0: [0,half) lane1: [half,adeg)
        int jb = par ? half : 0;
        int je = par ? adeg : half;
        int j = jb;
        if (uselds) {
            int ofs = s0 - sbeg;
            for (; j + 8 <= je; j += 8) {
                uint4 nA = *(const uint4*)&scsr[ofs + j];
                uint4 nB = *(const uint4*)&scsr[ofs + j + 4];
                uint4 r0 = up[nA.x], r1 = up[nA.y], r2 = up[nA.z], r3 = up[nA.w];
                uint4 r4 = up[nB.x], r5 = up[nB.y], r6 = up[nB.z], r7 = up[nB.w];
                acc8(a, r0); acc8(a, r1); acc8(a, r2); acc8(a, r3);
                acc8(a, r4); acc8(a, r5); acc8(a, r6); acc8(a, r7);
            }
            if (j < je) {
                uint4 nA = *(const uint4*)&scsr[ofs + j];
                uint4 r0 = up[nA.x], r1 = up[nA.y], r2 = up[nA.z], r3 = up[nA.w];
                acc8(a, r0); acc8(a, r1); acc8(a, r2); acc8(a, r3);
            }
        } else {
            for (; j + 8 <= je; j += 8) {
                uint4 nA = *(const uint4*)(csr + s0 + j);
                uint4 nB = *(const uint4*)(csr + s0 + j + 4);
                uint4 r0 = up[nA.x], r1 = up[nA.y], r2 = up[nA.z], r3 = up[nA.w];
                uint4 r4 = up[nB.x], r5 = up[nB.y], r6 = up[nB.z], r7 = up[nB.w];
                acc8(a, r0); acc8(a, r1); acc8(a, r2); acc8(a, r3);
                acc8(a, r4); acc8(a, r5); acc8(a, r6); acc8(a, r7);
            }
            if (j < je) {
                uint4 nA = *(const uint4*)(csr + s0 + j);
                uint4 r0 = up[nA.x], r1 = up[nA.y], r2 = up[nA.z], r3 = up[nA.w];
                acc8(a, r0); acc8(a, r1); acc8(a, r2); acc8(a, r3);
            }
        }
    }
    #pragma unroll
    for (int k = 0; k < 7; k++) a[k] += __shfl_xor(a[k], 1);   // combine halves
    if (i < N && par == 0) {
        float di = rsqrtf((float)(deg[i] + 1));
        #pragma unroll
        for (int k = 0; k < 7; k++) agg[team][k] = a[k] * di;
    }
    __syncthreads();
    int mbase = lb * 128 + ty * 32;
    for (int mm = 0; mm < 32; mm++) {
        int node = mbase + mm;
        if (node >= N) break;
        const float* ag = agg[ty * 32 + mm];
        float s = b;
        #pragma unroll
        for (int k = 0; k < 7; k++) s += ag[k] * Wsm[k * 64 + lane];
        h[(size_t)node * 64 + lane] = __float2bfloat16(s);
        sum += s; sq += s * s;
    }
    sm[0][ty][lane] = sum;
    sm[1][ty][lane] = sq;
    __syncthreads();
    if (ty == 0) {
        atomicAdd(&stat[lane],      sm[0][0][lane] + sm[0][1][lane] + sm[0][2][lane] + sm[0][3][lane]);
        atomicAdd(&stat[64 + lane], sm[1][0][lane] + sm[1][1][lane] + sm[1][2][lane] + sm[1][3][lane]);
    }
}

// ---- Layer 1 GEMM via MFMA, merged; y PAIR-MAJOR -----------------------
__global__ __launch_bounds__(256) void k_gemm1m(
    const bf16* h_c, const float* W_c, const float* stat_c, const float* gam_c,
    const float* bet_c, const int* deg_c, bf16* y_c, float invN_c, int N_c, int NY_c,
    const bf16* h_s, const float* W_s, const float* stat_s, const float* gam_s,
    const float* bet_s, const int* deg_s, bf16* y_s, float invN_s, int N_s, int NY_s,
    int nblk_c) {
    __shared__ short Wt[64][72];
    __shared__ float AB[128];
    const bf16* h; const float *W, *stat, *gam, *bet; const int* deg;
    bf16* y; float invN; int N, NY, lb, nb;
    if ((int)blockIdx.x < nblk_c) {
        lb = blockIdx.x; nb = nblk_c;
        h = h_c; W = W_c; stat = stat_c; gam = gam_c; bet = bet_c; deg = deg_c;
        y = y_c; invN = invN_c; N = N_c; NY = NY_c;
    } else {
        lb = blockIdx.x - nblk_c; nb = gridDim.x - nblk_c;
        h = h_s; W = W_s; stat = stat_s; gam = gam_s; bet = bet_s; deg = deg_s;
        y = y_s; invN = invN_s; N = N_s; NY = NY_s;
    }
    int t = threadIdx.x, lane = t & 63, ty = t >> 6;
    for (int i = t; i < 4096; i += 256) {
        int k = i >> 6, n = i & 63;
        Wt[n][k] = (short)f2bfbits(W[i]);
    }
    if (t < 64) {
        float mean = stat[t] * invN;
        float var = stat[64 + t] * invN - mean * mean;
        float A = gam[t] * rsqrtf(fmaxf(var, 0.f) + EPS_);
        AB[t] = A;
        AB[64 + t] = bet[t] - mean * A;
    }
    if (lb == 0 && t < 64) {     // zero sentinel row N of each pair
        int pr = t >> 4, cl = t & 15;
        y[((size_t)pr * NY + N) * 16 + cl] = __float2bfloat16(0.f);
    }
    __syncthreads();
    int quad = lane >> 4, l16 = lane & 15;
    short8 Bf[2][4];
    #pragma unroll
    for (int kt = 0; kt < 2; kt++)
        #pragma unroll
        for (int nt = 0; nt < 4; nt++) {
            int n = nt * 16 + l16, k0 = kt * 32 + quad * 8;
            Bf[kt][nt] = *(const short8*)&Wt[n][k0];
        }
    int ntile = (N + 63) >> 6;
    for (int tile = lb * 4 + ty; tile < ntile; tile += nb * 4) {
        int base = tile << 6;
        f32x4 acc[4][4];
        #pragma unroll
        for (int a = 0; a < 4; a++)
            #pragma unroll
            for (int b = 0; b < 4; b++) acc[a][b] = (f32x4){0.f, 0.f, 0.f, 0.f};
        #pragma unroll
        for (int kt = 0; kt < 2; kt++) {
            int k0 = kt * 32 + quad * 8;
            float Ak[8], Bk[8];
            #pragma unroll
            for (int j = 0; j < 8; j++) { Ak[j] = AB[k0 + j]; Bk[j] = AB[64 + k0 + j]; }
            #pragma unroll
            for (int mt = 0; mt < 4; mt++) {
                int node = base + mt * 16 + l16;     // tail overread: h padded
                uint4 raw = *(const uint4*)(h + (size_t)node * 64 + k0);
                unsigned rr[4] = {raw.x, raw.y, raw.z, raw.w};
                short8 af;
                #pragma unroll
                for (int j = 0; j < 8; j++) {
                    unsigned bits = (j & 1) ? (rr[j >> 1] & 0xffff0000u)
                                            : (rr[j >> 1] << 16);
                    float v = __uint_as_float(bits);
                    v = fmaxf(v * Ak[j] + Bk[j], 0.f);
                    af[j] = (short)f2bfbits(v);
                }
                #pragma unroll
                for (int nt = 0; nt < 4; nt++)
                    acc[mt][nt] = __builtin_amdgcn_mfma_f32_16x16x32_bf16(
                        af, Bf[kt][nt], acc[mt][nt], 0, 0, 0);
            }
        }
        #pragma unroll
        for (int mt = 0; mt < 4; mt++)
            #pragma unroll
            for (int r = 0; r < 4; r++) {
                int node = base + mt * 16 + quad * 4 + r;
                if (node < N) {
                    float dinv = rsqrtf((float)(deg[node] + 1));
                    #pragma unroll
                    for (int nt = 0; nt < 4; nt++)
                        y[((size_t)nt * NY + node) * 16 + l16] =
                            __float2bfloat16(acc[mt][nt][r] * dinv);
                }
            }
    }
}

// ---- Layer-1 gather: PAIR-MAJOR, 2-lane teams, LDS-staged csr ----------
__global__ __launch_bounds__(256) void k_gather16p(
    const bf16* y_c, const int* csr_c, const int* start_c, const int* deg_c,
    const float* bias_c, bf16* h_c, float* stat_c, int N_c, int NY_c,
    const bf16* y_s, const int* csr_s, const int* start_s, const int* deg_s,
    const float* bias_s, bf16* h_s, float* stat_s, int N_s, int NY_s,
    int nblk_c) {
    __shared__ float sms[4][2][2][8];
    __shared__ int scsr[4096];
    const bf16* y; const int *csr, *start, *deg; const float* bias;
    bf16* h; float* stat; int N, NY, lb, nb;
    if ((int)blockIdx.x < nblk_c) {
        lb = blockIdx.x; nb = nblk_c;
        y = y_c; csr = csr_c; start = start_c; deg = deg_c; bias = bias_c;
        h = h_c; stat = stat_c; N = N_c; NY = NY_c;
    } else {
        lb = blockIdx.x - nblk_c; nb = gridDim.x - nblk_c;
        y = y_s; csr = csr_s; start = start_s; deg = deg_s; bias = bias_s;
        h = h_s; stat = stat_s; N = N_s; NY = NY_s;
    }
    int t = threadIdx.x, lane = t & 63, ty = t >> 6;
    int team = lane >> 1, par = lane & 1;
    int pair = lb & 3;
    int grp = lb >> 2;
    int ngrp = nb >> 2;
    const uint4* yp = (const uint4*)y + (size_t)pair * NY * 2;
    uint4* hp = (uint4*)h + (size_t)pair * NY * 2;
    float b[8];
    #pragma unroll
    for (int k = 0; k < 8; k++) b[k] = bias[pair * 16 + par * 8 + k];
    float sum[8], sq[8];
    #pragma unroll
    for (int k = 0; k < 8; k++) { sum[k] = 0.f; sq[k] = 0.f; }
    for (int c0 = grp * 128; c0 < N; c0 += ngrp * 128) {
        int last = (c0 + 127 < N) ? c0 + 127 : N - 1;
        int sbeg = start[c0];
        int span = start[last] + ((deg[last] + 3) & ~3) - sbeg;
        bool uselds = (span <= 4096);
        if (uselds) {
            __syncthreads();                       // protect prior sweep's reads
            for (int w = t * 4; w < span; w += 1024)
                *(int4*)&scsr[w] = *(const int4*)(csr + sbeg + w);
            __syncthreads();
        }
        int i = c0 + ty * 32 + team;
        if (i <= last) {
            int dg = deg[i], s0 = start[i];
            int adeg = (dg + 3) & ~3;
            float a[8];
            #pragma unroll
            for (int k = 0; k < 8; k++) a[k] = 0.f;
            acc8(a, yp[2 * i + par]);                // self-loop
            int j = 0;
            if (uselds) {
                int ofs = s0 - sbeg;
                for (; j + 8 <= adeg; j += 8) {
                    uint4 nA = *(const uint4*)&scsr[ofs + j];
                    uint4 nB = *(const uint4*)&scsr[ofs + j + 4];
                    uint4 q0 = yp[2 * nA.x + par];
                    uint4 q1 = yp[2 * nA.y + par];
                    uint4 q2 = yp[2 * nA.z + par];
                    uint4 q3 = yp[2 * nA.w + par];
                    uint4 q4 = yp[2 * nB.x + par];
                    uint4 q5 = yp[2 * nB.y + par];
                    uint4 q6 = yp[2 * nB.z + par];
                    uint4 q7 = yp[2 * nB.w + par];
                    acc8(a, q0); acc8(a, q1); acc8(a, q2); acc8(a, q3);
                    acc8(a, q4); acc8(a, q5); acc8(a, q6); acc8(a, q7);
                }
                if (j < adeg) {
                    uint4 nA = *(const uint4*)&scsr[ofs + j];
                    uint4 q0 = yp[2 * nA.x + par];
                    uint4 q1 = yp[2 * nA.y + par];
                    uint4 q2 = yp[2 * nA.z + par];
                    uint4 q3 = yp[2 * nA.w + par];
                    acc8(a, q0); acc8(a, q1); acc8(a, q2); acc8(a, q3);
                }
            } else {
                for (; j + 8 <= adeg; j += 8) {
                    uint4 nA = *(const uint4*)(csr + s0 + j);
                    uint4 nB = *(const uint4*)(csr + s0 + j + 4);
                    uint4 q0 = yp[2 * nA.x + par];
                    uint4 q1 = yp[2 * nA.y + par];
                    uint4 q2 = yp[2 * nA.z + par];
                    uint4 q3 = yp[2 * nA.w + par];
                    uint4 q4 = yp[2 * nB.x + par];
                    uint4 q5 = yp[2 * nB.y + par];
                    uint4 q6 = yp[2 * nB.z + par];
                    uint4 q7 = yp[2 * nB.w + par];
                    acc8(a, q0); acc8(a, q1); acc8(a, q2); acc8(a, q3);
                    acc8(a, q4); acc8(a, q5); acc8(a, q6); acc8(a, q7);
                }
                if (j < adeg) {
                    uint4 nA = *(const uint4*)(csr + s0 + j);
                    uint4 q0 = yp[2 * nA.x + par];
                    uint4 q1 = yp[2 * nA.y + par];
                    uint4 q2 = yp[2 * nA.z + par];
                    uint4 q3 = yp[2 * nA.w + par];
                    acc8(a, q0); acc8(a, q1); acc8(a, q2); acc8(a, q3);
                }
            }
            float di = rsqrtf((float)(dg + 1));
            union __align__(16) Pack { bf16 hh[8]; uint4 v; } p;
            #pragma unroll
            for (int k = 0; k < 8; k++) {
                float v = a[k] * di + b[k];
                p.hh[k] = __float2bfloat16(v);
                sum[k] += v; sq[k] += v * v;
            }
            hp[2 * i + par] = p.v;
        }
    }
    #pragma unroll
    for (int k = 0; k < 8; k++) {
        float s1 = sum[k], s2 = sq[k];
        s1 += __shfl_down(s1, 32); s2 += __shfl_down(s2, 32);
        s1 += __shfl_down(s1, 16); s2 += __shfl_down(s2, 16);
        s1 += __shfl_down(s1, 8);  s2 += __shfl_down(s2, 8);
        s1 += __shfl_down(s1, 4);  s2 += __shfl_down(s2, 4);
        s1 += __shfl_down(s1, 2);  s2 += __shfl_down(s2, 2);
        if (lane < 2) { sms[ty][lane][0][k] = s1; sms[ty][lane][1][k] = s2; }
    }
    __syncthreads();
    if (t < 16) {
        int pp = t >> 3, k = t & 7;
        atomicAdd(&stat[pair * 16 + pp * 8 + k],
                  sms[0][pp][0][k] + sms[1][pp][0][k] + sms[2][pp][0][k] + sms[3][pp][0][k]);
    } else if (t >= 64 && t < 80) {
        int q = t - 64, pp = q >> 3, k = q & 7;
        atomicAdd(&stat[64 + pair * 16 + pp * 8 + k],
                  sms[0][pp][1][k] + sms[1][pp][1][k] + sms[2][pp][1][k] + sms[3][pp][1][k]);
    }
}

// ---- Pool merged: BN1+ReLU fused; reads h PAIR-MAJOR -------------------
__global__ __launch_bounds__(256) void k_poolm(
    const bf16* h_c, const float* stat_c, const float* gam_c, const float* bet_c,
    const int* batch_c, float* pooled_c, float* cnt_c, float invN_c, int N_c, int NY_c,
    const bf16* h_s, const float* stat_s, const float* gam_s, const float* bet_s,
    const int* batch_s, float* pooled_s, float* cnt_s, float invN_s, int N_s, int NY_s,
    int nblk_c) {
    const bf16* h; const float *stat, *gam, *bet; const int* batch;
    float *pooled, *cnt; float invN; int N, NY, lb, nb;
    if ((int)blockIdx.x < nblk_c) {
        lb = blockIdx.x; nb = nblk_c;
        h = h_c; stat = stat_c; gam = gam_c; bet = bet_c; batch = batch_c;
        pooled = pooled_c; cnt = cnt_c; invN = invN_c; N = N_c; NY = NY_c;
    } else {
        lb = blockIdx.x - nblk_c; nb = gridDim.x - nblk_c;
        h = h_s; stat = stat_s; gam = gam_s; bet = bet_s; batch = batch_s;
        pooled = pooled_s; cnt = cnt_s; invN = invN_s; N = N_s; NY = NY_s;
    }
    int t = threadIdx.x;
    int lane = t & 63;
    float mean = stat[lane] * invN;
    float var = stat[64 + lane] * invN - mean * mean;
    float A = gam[lane] * rsqrtf(fmaxf(var, 0.f) + EPS_);
    float B = bet[lane] - mean * A;
    size_t pbase = (size_t)(lane >> 4) * NY * 16 + (lane & 15);
    int w = (lb * 256 + t) >> 6;
    int nw = nb * 4;
    int chunk = (N + nw - 1) / nw;
    int i0 = w * chunk;
    int i1 = i0 + chunk;
    if (i1 > N) i1 = N;
    if (i0 >= N) return;
    int curg = batch[i0];
    float acc = 0.f, c = 0.f;
    for (int i = i0; i < i1; i++) {
        int g = batch[i];
        if (g != curg) {
            atomicAdd(&pooled[(size_t)curg * 64 + lane], acc);
            if (lane == 0) atomicAdd(&cnt[curg], c);
            curg = g; acc = 0.f; c = 0.f;
        }
        acc += fmaxf(b2f(h[pbase + (size_t)i * 16]) * A + B, 0.f);
        c += 1.f;
    }
    atomicAdd(&pooled[(size_t)curg * 64 + lane], acc);
    if (lane == 0) atomicAdd(&cnt[curg], c);
}

// ---- Head: 4 waves/block, one group per wave ---------------------------
__global__ __launch_bounds__(256) void k_head(const float* pooled_c, const float* cnt_c,
                                              const float* pooled_s, const float* cnt_s,
                                              const float* Wf1, const float* bf1_,
                                              const float* Wf2, const float* bf2_,
                                              float* out) {
    __shared__ float W1sm[128 * 64];
    __shared__ float W2sm[128];
    int t = threadIdx.x, lane = t & 63, w = t >> 6;
    for (int i = t; i < 128 * 64; i += 256) W1sm[i] = Wf1[i];
    if (t < 128) W2sm[t] = Wf2[t];
    __syncthreads();
    float bb1 = bf1_[lane];
    float b20 = bf2_[0];
    float b21 = bf2_[1];
    for (int g = blockIdx.x * 4 + w; g < G_; g += gridDim.x * 4) {
        float ic = 1.f / fmaxf(cnt_c[g], 1.f);
        float is = 1.f / fmaxf(cnt_s[g], 1.f);
        float hc = pooled_c[(size_t)g * 64 + lane] * ic;
        float hs = pooled_s[(size_t)g * 64 + lane] * is;
        float s = bb1;
        for (int k = 0; k < 64; k++) s += __shfl(hc, k) * W1sm[k * 64 + lane];
        for (int k = 0; k < 64; k++) s += __shfl(hs, k) * W1sm[(64 + k) * 64 + lane];
        s = fmaxf(s, 0.f);
        float p0 = s * W2sm[lane * 2 + 0];
        float p1 = s * W2sm[lane * 2 + 1];
        for (int off = 32; off > 0; off >>= 1) {
            p0 += __shfl_down(p0, off);
            p1 += __shfl_down(p1, off);
        }
        if (lane == 0) {
            out[g * 2 + 0] = p0 + b20;
            out[g * 2 + 1] = p1 + b21;
        }
    }
}

extern "C" void kernel_launch(void* const* d_in, const int* in_sizes, int n_in,
                              void* d_out, int out_size, void* d_ws, size_t ws_size,
                              hipStream_t stream) {
    float* out = (float*)d_out;

    if (n_in != 26 || in_sizes[0] != NC_ * 7 || in_sizes[1] != 2 * EC_ ||
        in_sizes[2] != NC_ || in_sizes[3] != NS_ * 7 || in_sizes[4] != 2 * ES_ ||
        in_sizes[5] != NS_ || out_size != G_ * 2) {
        k_fillout<<<(out_size + 255) / 256, 256, 0, stream>>>(out, 7777.0f, out_size);
        return;
    }
    if (ws_size < (size_t)WS_MIN_FALLBACK) {
        k_fillout<<<(out_size + 255) / 256, 256, 0, stream>>>(
            out, 1000.0f + (float)(ws_size >> 20), out_size);
        return;
    }
    const bool big = (ws_size >= (size_t)WS_BIG);

    const float* x_c     = (const float*)d_in[0];
    const int*   ei_c    = (const int*)d_in[1];
    const int*   batch_c = (const int*)d_in[2];
    const float* x_s     = (const float*)d_in[3];
    const int*   ei_s    = (const int*)d_in[4];
    const int*   batch_s = (const int*)d_in[5];
    const float* Wc0  = (const float*)d_in[6];
    const float* bc0  = (const float*)d_in[7];
    const float* gc0  = (const float*)d_in[8];
    const float* bec0 = (const float*)d_in[9];
    const float* Wc1  = (const float*)d_in[10];
    const float* bc1  = (const float*)d_in[11];
    const float* gc1  = (const float*)d_in[12];
    const float* bec1 = (const float*)d_in[13];
    const float* Ws0  = (const float*)d_in[14];
    const float* bs0  = (const float*)d_in[15];
    const float* gs0  = (const float*)d_in[16];
    const float* bes0 = (const float*)d_in[17];
    const float* Ws1  = (const float*)d_in[18];
    const float* bs1  = (const float*)d_in[19];
    const float* gs1  = (const float*)d_in[20];
    const float* bes1 = (const float*)d_in[21];
    const float* Wf1  = (const float*)d_in[22];
    const float* bf1_ = (const float*)d_in[23];
    const float* Wf2  = (const float*)d_in[24];
    const float* bf2_ = (const float*)d_in[25];

    const int NYC = NC_ + 8;
    const int NYS = NS_ + 8;

    // ---- workspace layout: bf16 buffers FIRST (aligned rows) -----------
    int* wsw = (int*)d_ws;
    size_t off = big ? (size_t)(3201024 + 3200256 + 1601536 + 1600256)
                     : (size_t)(3201024 + 3200256);
    float* stats_c  = (float*)(wsw + off); off += 256;
    float* stats_s  = (float*)(wsw + off); off += 256;
    float* pooled_c = (float*)(wsw + off); off += (size_t)G_ * 64;
    float* pooled_s = (float*)(wsw + off); off += (size_t)G_ * 64;
    float* cnt_c    = (float*)(wsw + off); off += G_;
    float* cnt_s    = (float*)(wsw + off); off += G_;
    int*   bcnt_c   = wsw + off; off += NB_C;
    int*   bcnt_s   = wsw + off; off += NB_S;
    const int zero_words = 256 + 256 + G_ * 64 * 2 + G_ * 2 + NB_C + NB_S;
    int*   bbase_c  = wsw + off; off += NB_C + 1;
    int*   bcur_c   = wsw + off; off += NB_C;
    int*   bbase_s  = wsw + off; off += NB_S + 1;
    int*   bcur_s   = wsw + off; off += NB_S;
    int*   deg_c    = wsw + off; off += NC_;
    int*   start_c  = wsw + off; off += NC_;
    int*   deg_s    = wsw + off; off += NS_;
    int*   start_s  = wsw + off; off += NS_;
    int*   csr_c    = wsw + off; off += CSR_WC;
    int*   csr_s    = wsw + off; off += CSR_WS;

    k_zero<<<512, 256, 0, stream>>>((int*)stats_c, zero_words);
    k_bhist2<<<96, 256, 0, stream>>>(ei_c + EC_, bcnt_c, ei_s + ES_, bcnt_s);
    k_bscan<<<1, 256, 0, stream>>>(bcnt_c, bbase_c, bcur_c, NB_C,
                                   bcnt_s, bbase_s, bcur_s, NB_S);

    if (big) {
        // ---- big layout: separate solvent buffers, merged pipeline ----
        bf16* h_c = (bf16*)wsw;                               // 3201024 words
        bf16* y_c = (bf16*)(wsw + 3201024);                   // 3200256 words
        bf16* h_s = (bf16*)(wsw + 3201024 + 3200256);         // 1601536 words
        bf16* y_s = (bf16*)(wsw + 3201024 + 3200256 + 1601536); // 1600256 words
        int*  ebuf_c = (int*)h_c;                 // dead before gather7m writes h_c
        int*  ebuf_s = (int*)h_c + 1600000;
        bf16* u_c = y_c;                          // dead before gemm1m writes y_c
        bf16* u_s = y_s;

        k_bin2<<<294, 256, 0, stream>>>(ei_c, bcur_c, ebuf_c, ei_s, bcur_s, ebuf_s);
        k_build2<<<NB_C + NB_S, 256, 0, stream>>>(bbase_c, ebuf_c, x_c, u_c,
                                                  deg_c, start_c, csr_c,
                                                  bbase_s, ebuf_s, x_s, u_s,
                                                  deg_s, start_s, csr_s);
        k_gather7m<<<NB_C + NB_S, 256, 0, stream>>>(
            u_c, csr_c, start_c, deg_c, Wc0, bc0, h_c, stats_c, NC_,
            u_s, csr_s, start_s, deg_s, Ws0, bs0, h_s, stats_s, NS_, NB_C);
        k_gemm1m<<<768, 256, 0, stream>>>(
            h_c, Wc1, stats_c, gc0, bec0, deg_c, y_c, 1.0f / NC_, NC_, NYC,
            h_s, Ws1, stats_s, gs0, bes0, deg_s, y_s, 1.0f / NS_, NS_, NYS, 512);
        k_gather16p<<<1024 + 512, 256, 0, stream>>>(
            y_c, csr_c, start_c, deg_c, bc1, h_c, stats_c + 128, NC_, NYC,
            y_s, csr_s, start_s, deg_s, bs1, h_s, stats_s + 128, NS_, NYS, 1024);
        k_poolm<<<384, 256, 0, stream>>>(
            h_c, stats_c + 128, gc1, bec1, batch_c, pooled_c, cnt_c, 1.0f / NC_, NC_, NYC,
            h_s, stats_s + 128, gs1, bes1, batch_s, pooled_s, cnt_s, 1.0f / NS_, NS_, NYS, 256);
    } else {
        // ---- fallback: shared buffers, sequential branches ----
        bf16* hbuf = (bf16*)wsw;
        bf16* ybuf = (bf16*)(wsw + 3201024);
        int*  ebuf_c = (int*)hbuf;
        int*  ebuf_s = (int*)hbuf + 1600000;
        bf16* ub = ybuf;

        k_bin2<<<294, 256, 0, stream>>>(ei_c, bcur_c, ebuf_c, ei_s, bcur_s, ebuf_s);
        k_build2<<<NB_C + NB_S, 256, 0, stream>>>(bbase_c, ebuf_c, x_c, ub,
                                                  deg_c, start_c, csr_c,
                                                  bbase_s, ebuf_s, (const float*)0, (bf16*)0,
                                                  deg_s, start_s, csr_s);
        // chromo
        k_gather7m<<<NB_C, 256, 0, stream>>>(
            ub, csr_c, start_c, deg_c, Wc0, bc0, hbuf, stats_c, NC_,
            ub, csr_c, start_c, deg_c, Wc0, bc0, hbuf, stats_c, NC_, NB_C);
        k_gemm1m<<<512, 256, 0, stream>>>(
            hbuf, Wc1, stats_c, gc0, bec0, deg_c, ybuf, 1.0f / NC_, NC_, NYC,
            hbuf, Wc1, stats_c, gc0, bec0, deg_c, ybuf, 1.0f / NC_, NC_, NYC, 512);
        k_gather16p<<<1024, 256, 0, stream>>>(
            ybuf, csr_c, start_c, deg_c, bc1, hbuf, stats_c + 128, NC_, NYC,
            ybuf, csr_c, start_c, deg_c, bc1, hbuf, stats_c + 128, NC_, NYC, 1024);
        k_poolm<<<256, 256, 0, stream>>>(
            hbuf, stats_c + 128, gc1, bec1, batch_c, pooled_c, cnt_c, 1.0f / NC_, NC_, NYC,
            hbuf, stats_c + 128, gc1, bec1, batch_c, pooled_c, cnt_c, 1.0f / NC_, NC_, NYC, 256);
        // solvent
        k_prep7<<<(NS_ + 256) / 256, 256, 0, stream>>>(x_s, deg_s, ub, NS_);
        k_gather7m<<<NB_S, 256, 0, stream>>>(
            ub, csr_s, start_s, deg_s, Ws0, bs0, hbuf, stats_s, NS_,
            ub, csr_s, start_s, deg_s, Ws0, bs0, hbuf, stats_s, NS_, NB_S);
        k_gemm1m<<<256, 256, 0, stream>>>(
            hbuf, Ws1, stats_s, gs0, bes0, deg_s, ybuf, 1.0f / NS_, NS_, NYS,
            hbuf, Ws1, stats_s, gs0, bes0, deg_s, ybuf, 1.0f / NS_, NS_, NYS, 256);
        k_gather16p<<<512, 256, 0, stream>>>(
            ybuf, csr_s, start_s, deg_s, bs1, hbuf, stats_s + 128, NS_, NYS,
            ybuf, csr_s, start_s, deg_s, bs1, hbuf, stats_s + 128, NS_, NYS, 512);
        k_poolm<<<256, 256, 0, stream>>>(
            hbuf, stats_s + 128, gs1, bes1, batch_s, pooled_s, cnt_s, 1.0f / NS_, NS_, NYS,
            hbuf, stats_s + 128, gs1, bes1, batch_s, pooled_s, cnt_s, 1.0f / NS_, NS_, NYS, 256);
    }

    k_head<<<256, 256, 0, stream>>>(pooled_c, cnt_c, pooled_s, cnt_s, Wf1, bf1_, Wf2, bf2_, out);
}

// Round 6
// 378.340 us; speedup vs baseline: 1.6067x; 1.1680x over previous
//
#include <hip/hip_runtime.h>
#include <hip/hip_bf16.h>

typedef __hip_bfloat16 bf16;
typedef __attribute__((ext_vector_type(8))) short short8;
typedef __attribute__((ext_vector_type(4))) float f32x4;

#define NC_ 100000
#define EC_ 1600000
#define NS_ 50000
#define ES_ 800000
#define G_  1024
#define EPS_ 1e-5f

#define NB_C 782
#define NB_S 391
#define NBMAX 782
#define KSL 8
#define CSR_WC 2000400    // EC_ + 512*NB_C + 16
#define CSR_WS 1000208    // ES_ + 512*NB_S + 16

#define WS_MIN_FALLBACK 39356176ull
#define WS_BIG          52163344ull

__device__ __forceinline__ float b2f(bf16 v) { return __bfloat162float(v); }

__device__ __forceinline__ unsigned short f2bfbits(float v) {
    bf16 b = __float2bfloat16(v);
    union { bf16 b; unsigned short u; } c; c.b = b; return c.u;
}

__device__ __forceinline__ void acc8(float* a, uint4 r) {
    a[0] += __uint_as_float(r.x << 16); a[1] += __uint_as_float(r.x & 0xffff0000u);
    a[2] += __uint_as_float(r.y << 16); a[3] += __uint_as_float(r.y & 0xffff0000u);
    a[4] += __uint_as_float(r.z << 16); a[5] += __uint_as_float(r.z & 0xffff0000u);
    a[6] += __uint_as_float(r.w << 16); a[7] += __uint_as_float(r.w & 0xffff0000u);
}

__global__ void DualGNN_31327491457689_kernel() {}

__global__ __launch_bounds__(256) void k_fillout(float* out, float val, int n) {
    int i = blockIdx.x * 256 + threadIdx.x;
    if (i < n) out[i] = val;
}

__global__ __launch_bounds__(256) void k_zero(int* p, int n) {
    int i = blockIdx.x * 256 + threadIdx.x;
    int stride = gridDim.x * 256;
    while (i < n) { p[i] = 0; i += stride; }
}

// ---- Phase A: bucket histograms, both branches -------------------------
__global__ __launch_bounds__(256) void k_bhist2(const int* dst_c, int* bcnt_c,
                                                const int* dst_s, int* bcnt_s) {
    __shared__ int h[NBMAX];
    int t = threadIdx.x;
    const int* dst; int* bcnt; int E, NB, b0, nb;
    if (blockIdx.x < 256) { dst = dst_c; bcnt = bcnt_c; E = EC_; NB = NB_C; b0 = blockIdx.x; nb = 256; }
    else { dst = dst_s; bcnt = bcnt_s; E = ES_; NB = NB_S; b0 = blockIdx.x - 256; nb = 128; }
    for (int i = t; i < NB; i += 256) h[i] = 0;
    __syncthreads();
    for (int e = b0 * 256 + t; e < E; e += nb * 256)
        atomicAdd(&h[dst[e] >> 7], 1);
    __syncthreads();
    for (int i = t; i < NB; i += 256) {
        int v = h[i];
        if (v) atomicAdd(&bcnt[i], v);
    }
}

// ---- Phase B: scan bucket counts ---------------------------------------
__device__ void scan_one(const int* cnt, int* base, int* cur, int NB, int (*sc)[1024]) {
    int t = threadIdx.x;
    for (int i = t; i < 1024; i += 256) sc[0][i] = (i < NB) ? cnt[i] : 0;
    __syncthreads();
    int pin = 0;
    for (int off = 1; off < 1024; off <<= 1) {
        for (int i = t; i < 1024; i += 256) {
            int v = sc[pin][i];
            if (i >= off) v += sc[pin][i - off];
            sc[1 - pin][i] = v;
        }
        __syncthreads();
        pin ^= 1;
    }
    for (int i = t; i <= NB; i += 256) {
        int e = (i == 0) ? 0 : sc[pin][i - 1];
        base[i] = e;
        if (i < NB) cur[i] = e;
    }
    __syncthreads();
}

__global__ __launch_bounds__(256) void k_bscan(const int* cnt_c, int* base_c, int* cur_c, int NBc,
                                               const int* cnt_s, int* base_s, int* cur_s, int NBs) {
    __shared__ int sc[2][1024];
    scan_one(cnt_c, base_c, cur_c, NBc, sc);
    scan_one(cnt_s, base_s, cur_s, NBs, sc);
}

// ---- Phase C: bin packed edges. 1173 blocks x 2048 edges, KSL=8:
// LDS 28 KB (was 53) -> 5 blocks/CU; ~18 waves/CU vs ~9. bin2 is
// latency-bound (VALUBusy 0.9%, HBM 4% at 294 blocks) -> waves are
// the lever. Mean bucket fill 2.6 -> KSL=8 almost never spills. -------
__global__ __launch_bounds__(256) void k_bin2(const int* ei_c, int* bcur_c, int* ebuf_c,
                                              const int* ei_s, int* bcur_s, int* ebuf_s) {
    __shared__ int cnt[NBMAX];
    __shared__ int slot[NBMAX * KSL];
    int t = threadIdx.x;
    const int *src, *dst; int *bcur, *ebuf; int E, NB; int base;
    if (blockIdx.x < 782) {
        src = ei_c; dst = ei_c + EC_; bcur = bcur_c; ebuf = ebuf_c;
        E = EC_; NB = NB_C; base = blockIdx.x * 2048;
    } else {
        src = ei_s; dst = ei_s + ES_; bcur = bcur_s; ebuf = ebuf_s;
        E = ES_; NB = NB_S; base = (blockIdx.x - 782) * 2048;
    }
    if (base >= E) return;
    for (int i = t; i < NB; i += 256) cnt[i] = 0;
    __syncthreads();
    int e1 = base + 2048;
    if (e1 > E) e1 = E;
    for (int e = base + t; e < e1; e += 256) {
        int d = dst[e];
        int p = ((d & 127) << 24) | src[e];
        int b = d >> 7;
        int sl = atomicAdd(&cnt[b], 1);
        if (sl < KSL) slot[b * KSL + sl] = p;
        else { int gp = atomicAdd(&bcur[b], 1); ebuf[gp] = p; }
    }
    __syncthreads();
    for (int b = t; b < NB; b += 256) {
        int c = cnt[b];
        if (c > KSL) c = KSL;
        if (c > 0) {
            int gp = atomicAdd(&bcur[b], c);
            for (int k = 0; k < c; k++) ebuf[gp + k] = slot[b * KSL + k];
        }
    }
}

// ---- Phase D: per-bucket build + u prep (both branches) ----------------
__global__ __launch_bounds__(256) void k_build2(const int* bbase_c, const int* ebuf_c,
                                                const float* x_c, bf16* u_c,
                                                int* deg_c, int* start_c, int* csr_c,
                                                const int* bbase_s, const int* ebuf_s,
                                                const float* x_s, bf16* u_s,
                                                int* deg_s, int* start_s, int* csr_s) {
    __shared__ int lcnt[128], lofs[128], lcur[128];
    int t = threadIdx.x;
    const int* bbase; const int* ebuf; const float* x; bf16* u;
    int* deg; int* start; int* csr; int N, b;
    if (blockIdx.x < NB_C) {
        b = blockIdx.x; bbase = bbase_c; ebuf = ebuf_c; x = x_c; u = u_c;
        deg = deg_c; start = start_c; csr = csr_c; N = NC_;
    } else {
        b = blockIdx.x - NB_C; bbase = bbase_s; ebuf = ebuf_s; x = x_s; u = u_s;
        deg = deg_s; start = start_s; csr = csr_s; N = NS_;
    }
    int e0 = bbase[b], e1 = bbase[b + 1];
    int cb = ((e0 + 512 * b) + 3) & ~3;
    int n0 = b << 7;
    if (t < 128) lcnt[t] = 0;
    __syncthreads();
    for (int e = e0 + t; e < e1; e += 256)
        atomicAdd(&lcnt[((unsigned)ebuf[e]) >> 24], 1);
    __syncthreads();
    if (t < 64) {
        int c0 = lcnt[2 * t], c1 = lcnt[2 * t + 1];
        int v0 = (c0 + 3) & ~3, v1 = (c1 + 3) & ~3;
        int s = v0 + v1, incl = s;
        for (int off = 1; off < 64; off <<= 1) {
            int uu = __shfl_up(incl, off);
            if (t >= off) incl += uu;
        }
        int excl = incl - s;
        lofs[2 * t] = excl;
        lofs[2 * t + 1] = excl + v0;
    }
    __syncthreads();
    if (t < 128) {
        int node = n0 + t;
        if (node < N) {
            deg[node] = lcnt[t];
            start[node] = cb + lofs[t];
            if (x) {
                float d = rsqrtf((float)(lcnt[t] + 1));
                union __align__(16) Pack { bf16 hh[8]; uint4 v; } p;
                for (int k = 0; k < 7; k++) p.hh[k] = __float2bfloat16(x[node * 7 + k] * d);
                p.hh[7] = __float2bfloat16(0.f);
                ((uint4*)u)[node] = p.v;
            }
        }
        lcur[t] = lofs[t];
    }
    __syncthreads();
    if (t < 128) {
        int c = lcnt[t], al = (c + 3) & ~3;
        for (int k = c; k < al; k++) csr[cb + lofs[t] + k] = N;
    }
    for (int e = e0 + t; e < e1; e += 256) {
        unsigned p = (unsigned)ebuf[e];
        int dl = p >> 24;
        int pos = atomicAdd(&lcur[dl], 1);
        csr[cb + pos] = (int)(p & 0xFFFFFF);
    }
    if (b == 0 && t < 4 && u && x) ((int*)u)[N * 4 + t] = 0;   // zero sentinel row
}

// ---- u prep (fallback path only) ---------------------------------------
__global__ __launch_bounds__(256) void k_prep7(const float* x, const int* deg,
                                               bf16* u, int N) {
    int i = blockIdx.x * 256 + threadIdx.x;
    if (i > N) return;
    union __align__(16) Pack { bf16 hh[8]; uint4 v; } p;
    if (i == N) {
        p.v = (uint4){0u, 0u, 0u, 0u};
    } else {
        float d = rsqrtf((float)(deg[i] + 1));
        for (int k = 0; k < 7; k++) p.hh[k] = __float2bfloat16(x[i * 7 + k] * d);
        p.hh[7] = __float2bfloat16(0.f);
    }
    ((uint4*)u)[i] = p.v;
}

// ---- Layer 0 gather (rank-7) + fused 7x64 GEMM, 2-lane teams, merged ---
__global__ __launch_bounds__(256) void k_gather7m(
    const bf16* u_c, const int* csr_c, const int* start_c, const int* deg_c,
    const float* W_c, const float* bias_c, bf16* h_c, float* stat_c, int N_c,
    const bf16* u_s, const int* csr_s, const int* start_s, const int* deg_s,
    const float* W_s, const float* bias_s, bf16* h_s, float* stat_s, int N_s,
    int nblk_c) {
    __shared__ float Wsm[7 * 64];
    __shared__ float agg[128][9];
    __shared__ float sm[2][4][64];
    __shared__ int scsr[4096];
    const bf16* u; const int *csr, *start, *deg; const float *W, *bias;
    bf16* h; float* stat; int N, lb;
    if ((int)blockIdx.x < nblk_c) {
        lb = blockIdx.x; u = u_c; csr = csr_c; start = start_c; deg = deg_c;
        W = W_c; bias = bias_c; h = h_c; stat = stat_c; N = N_c;
    } else {
        lb = blockIdx.x - nblk_c; u = u_s; csr = csr_s; start = start_s; deg = deg_s;
        W = W_s; bias = bias_s; h = h_s; stat = stat_s; N = N_s;
    }
    int t = threadIdx.x, lane = t & 63, ty = t >> 6;
    int team = t >> 1, par = t & 1;
    for (int i = t; i < 448; i += 256) Wsm[i] = W[i];
    float b = bias[lane];
    float sum = 0.f, sq = 0.f;
    const uint4* up = (const uint4*)u;
    // stage this bucket's contiguous csr span
    int n0 = lb * 128;
    int last = (n0 + 127 < N) ? n0 + 127 : N - 1;
    int sbeg = start[n0];
    int span = start[last] + ((deg[last] + 3) & ~3) - sbeg;
    bool uselds = (span <= 4096);
    if (uselds) {
        for (int w = t * 4; w < span; w += 1024)
            *(int4*)&scsr[w] = *(const int4*)(csr + sbeg + w);
    }
    __syncthreads();
    int i = n0 + team;
    float a[8] = {0.f, 0.f, 0.f, 0.f, 0.f, 0.f, 0.f, 0.f};
    if (i < N) {
        int dg = deg[i], s0 = start[i];
        int adeg = (dg + 3) & ~3;
        if (par == 0) acc8(a, up[i]);            // self-loop term
        int half = ((adeg >> 1) + 3) & ~3;       // lane0: [0,half) lane1: [half,adeg)
        int jb = par ? half : 0;
        int je = par ? adeg : half;
        int j = jb;
        if (uselds) {
            int ofs = s0 - sbeg;
            for (; j + 8 <= je; j += 8) {
                uint4 nA = *(const uint4*)&scsr[ofs + j];
                uint4 nB = *(const uint4*)&scsr[ofs + j + 4];
                uint4 r0 = up[nA.x], r1 = up[nA.y], r2 = up[nA.z], r3 = up[nA.w];
                uint4 r4 = up[nB.x], r5 = up[nB.y], r6 = up[nB.z], r7 = up[nB.w];
                acc8(a, r0); acc8(a, r1); acc8(a, r2); acc8(a, r3);
                acc8(a, r4); acc8(a, r5); acc8(a, r6); acc8(a, r7);
            }
            if (j < je) {
                uint4 nA = *(const uint4*)&scsr[ofs + j];
                uint4 r0 = up[nA.x], r1 = up[nA.y], r2 = up[nA.z], r3 = up[nA.w];
                acc8(a, r0); acc8(a, r1); acc8(a, r2); acc8(a, r3);
            }
        } else {
            for (; j + 8 <= je; j += 8) {
                uint4 nA = *(const uint4*)(csr + s0 + j);
                uint4 nB = *(const uint4*)(csr + s0 + j + 4);
                uint4 r0 = up[nA.x], r1 = up[nA.y], r2 = up[nA.z], r3 = up[nA.w];
                uint4 r4 = up[nB.x], r5 = up[nB.y], r6 = up[nB.z], r7 = up[nB.w];
                acc8(a, r0); acc8(a, r1); acc8(a, r2); acc8(a, r3);
                acc8(a, r4); acc8(a, r5); acc8(a, r6); acc8(a, r7);
            }
            if (j < je) {
                uint4 nA = *(const uint4*)(csr + s0 + j);
                uint4 r0 = up[nA.x], r1 = up[nA.y], r2 = up[nA.z], r3 = up[nA.w];
                acc8(a, r0); acc8(a, r1); acc8(a, r2); acc8(a, r3);
            }
        }
    }
    #pragma unroll
    for (int k = 0; k < 7; k++) a[k] += __shfl_xor(a[k], 1);   // combine halves
    if (i < N && par == 0) {
        float di = rsqrtf((float)(deg[i] + 1));
        #pragma unroll
        for (int k = 0; k < 7; k++) agg[team][k] = a[k] * di;
    }
    __syncthreads();
    int mbase = lb * 128 + ty * 32;
    for (int mm = 0; mm < 32; mm++) {
        int node = mbase + mm;
        if (node >= N) break;
        const float* ag = agg[ty * 32 + mm];
        float s = b;
        #pragma unroll
        for (int k = 0; k < 7; k++) s += ag[k] * Wsm[k * 64 + lane];
        h[(size_t)node * 64 + lane] = __float2bfloat16(s);
        sum += s; sq += s * s;
    }
    sm[0][ty][lane] = sum;
    sm[1][ty][lane] = sq;
    __syncthreads();
    if (ty == 0) {
        atomicAdd(&stat[lane],      sm[0][0][lane] + sm[0][1][lane] + sm[0][2][lane] + sm[0][3][lane]);
        atomicAdd(&stat[64 + lane], sm[1][0][lane] + sm[1][1][lane] + sm[1][2][lane] + sm[1][3][lane]);
    }
}

// ---- Layer 1 GEMM via MFMA, merged; y PAIR-MAJOR -----------------------
__global__ __launch_bounds__(256) void k_gemm1m(
    const bf16* h_c, const float* W_c, const float* stat_c, const float* gam_c,
    const float* bet_c, const int* deg_c, bf16* y_c, float invN_c, int N_c, int NY_c,
    const bf16* h_s, const float* W_s, const float* stat_s, const float* gam_s,
    const float* bet_s, const int* deg_s, bf16* y_s, float invN_s, int N_s, int NY_s,
    int nblk_c) {
    __shared__ short Wt[64][72];
    __shared__ float AB[128];
    const bf16* h; const float *W, *stat, *gam, *bet; const int* deg;
    bf16* y; float invN; int N, NY, lb, nb;
    if ((int)blockIdx.x < nblk_c) {
        lb = blockIdx.x; nb = nblk_c;
        h = h_c; W = W_c; stat = stat_c; gam = gam_c; bet = bet_c; deg = deg_c;
        y = y_c; invN = invN_c; N = N_c; NY = NY_c;
    } else {
        lb = blockIdx.x - nblk_c; nb = gridDim.x - nblk_c;
        h = h_s; W = W_s; stat = stat_s; gam = gam_s; bet = bet_s; deg = deg_s;
        y = y_s; invN = invN_s; N = N_s; NY = NY_s;
    }
    int t = threadIdx.x, lane = t & 63, ty = t >> 6;
    for (int i = t; i < 4096; i += 256) {
        int k = i >> 6, n = i & 63;
        Wt[n][k] = (short)f2bfbits(W[i]);
    }
    if (t < 64) {
        float mean = stat[t] * invN;
        float var = stat[64 + t] * invN - mean * mean;
        float A = gam[t] * rsqrtf(fmaxf(var, 0.f) + EPS_);
        AB[t] = A;
        AB[64 + t] = bet[t] - mean * A;
    }
    if (lb == 0 && t < 64) {     // zero sentinel row N of each pair
        int pr = t >> 4, cl = t & 15;
        y[((size_t)pr * NY + N) * 16 + cl] = __float2bfloat16(0.f);
    }
    __syncthreads();
    int quad = lane >> 4, l16 = lane & 15;
    short8 Bf[2][4];
    #pragma unroll
    for (int kt = 0; kt < 2; kt++)
        #pragma unroll
        for (int nt = 0; nt < 4; nt++) {
            int n = nt * 16 + l16, k0 = kt * 32 + quad * 8;
            Bf[kt][nt] = *(const short8*)&Wt[n][k0];
        }
    int ntile = (N + 63) >> 6;
    for (int tile = lb * 4 + ty; tile < ntile; tile += nb * 4) {
        int base = tile << 6;
        f32x4 acc[4][4];
        #pragma unroll
        for (int a = 0; a < 4; a++)
            #pragma unroll
            for (int b = 0; b < 4; b++) acc[a][b] = (f32x4){0.f, 0.f, 0.f, 0.f};
        #pragma unroll
        for (int kt = 0; kt < 2; kt++) {
            int k0 = kt * 32 + quad * 8;
            float Ak[8], Bk[8];
            #pragma unroll
            for (int j = 0; j < 8; j++) { Ak[j] = AB[k0 + j]; Bk[j] = AB[64 + k0 + j]; }
            #pragma unroll
            for (int mt = 0; mt < 4; mt++) {
                int node = base + mt * 16 + l16;     // tail overread: h padded
                uint4 raw = *(const uint4*)(h + (size_t)node * 64 + k0);
                unsigned rr[4] = {raw.x, raw.y, raw.z, raw.w};
                short8 af;
                #pragma unroll
                for (int j = 0; j < 8; j++) {
                    unsigned bits = (j & 1) ? (rr[j >> 1] & 0xffff0000u)
                                            : (rr[j >> 1] << 16);
                    float v = __uint_as_float(bits);
                    v = fmaxf(v * Ak[j] + Bk[j], 0.f);
                    af[j] = (short)f2bfbits(v);
                }
                #pragma unroll
                for (int nt = 0; nt < 4; nt++)
                    acc[mt][nt] = __builtin_amdgcn_mfma_f32_16x16x32_bf16(
                        af, Bf[kt][nt], acc[mt][nt], 0, 0, 0);
            }
        }
        #pragma unroll
        for (int mt = 0; mt < 4; mt++)
            #pragma unroll
            for (int r = 0; r < 4; r++) {
                int node = base + mt * 16 + quad * 4 + r;
                if (node < N) {
                    float dinv = rsqrtf((float)(deg[node] + 1));
                    #pragma unroll
                    for (int nt = 0; nt < 4; nt++)
                        y[((size_t)nt * NY + node) * 16 + l16] =
                            __float2bfloat16(acc[mt][nt][r] * dinv);
                }
            }
    }
}

// ---- Layer-1 gather: PAIR-MAJOR, 2-lane teams, LDS-staged csr ----------
__global__ __launch_bounds__(256) void k_gather16p(
    const bf16* y_c, const int* csr_c, const int* start_c, const int* deg_c,
    const float* bias_c, bf16* h_c, float* stat_c, int N_c, int NY_c,
    const bf16* y_s, const int* csr_s, const int* start_s, const int* deg_s,
    const float* bias_s, bf16* h_s, float* stat_s, int N_s, int NY_s,
    int nblk_c) {
    __shared__ float sms[4][2][2][8];
    __shared__ int scsr[4096];
    const bf16* y; const int *csr, *start, *deg; const float* bias;
    bf16* h; float* stat; int N, NY, lb, nb;
    if ((int)blockIdx.x < nblk_c) {
        lb = blockIdx.x; nb = nblk_c;
        y = y_c; csr = csr_c; start = start_c; deg = deg_c; bias = bias_c;
        h = h_c; stat = stat_c; N = N_c; NY = NY_c;
    } else {
        lb = blockIdx.x - nblk_c; nb = gridDim.x - nblk_c;
        y = y_s; csr = csr_s; start = start_s; deg = deg_s; bias = bias_s;
        h = h_s; stat = stat_s; N = N_s; NY = NY_s;
    }
    int t = threadIdx.x, lane = t & 63, ty = t >> 6;
    int team = lane >> 1, par = lane & 1;
    int pair = lb & 3;
    int grp = lb >> 2;
    int ngrp = nb >> 2;
    const uint4* yp = (const uint4*)y + (size_t)pair * NY * 2;
    uint4* hp = (uint4*)h + (size_t)pair * NY * 2;
    float b[8];
    #pragma unroll
    for (int k = 0; k < 8; k++) b[k] = bias[pair * 16 + par * 8 + k];
    float sum[8], sq[8];
    #pragma unroll
    for (int k = 0; k < 8; k++) { sum[k] = 0.f; sq[k] = 0.f; }
    for (int c0 = grp * 128; c0 < N; c0 += ngrp * 128) {
        int last = (c0 + 127 < N) ? c0 + 127 : N - 1;
        int sbeg = start[c0];
        int span = start[last] + ((deg[last] + 3) & ~3) - sbeg;
        bool uselds = (span <= 4096);
        if (uselds) {
            __syncthreads();                       // protect prior sweep's reads
            for (int w = t * 4; w < span; w += 1024)
                *(int4*)&scsr[w] = *(const int4*)(csr + sbeg + w);
            __syncthreads();
        }
        int i = c0 + ty * 32 + team;
        if (i <= last) {
            int dg = deg[i], s0 = start[i];
            int adeg = (dg + 3) & ~3;
            float a[8];
            #pragma unroll
            for (int k = 0; k < 8; k++) a[k] = 0.f;
            acc8(a, yp[2 * i + par]);                // self-loop
            int j = 0;
            if (uselds) {
                int ofs = s0 - sbeg;
                for (; j + 8 <= adeg; j += 8) {
                    uint4 nA = *(const uint4*)&scsr[ofs + j];
                    uint4 nB = *(const uint4*)&scsr[ofs + j + 4];
                    uint4 q0 = yp[2 * nA.x + par];
                    uint4 q1 = yp[2 * nA.y + par];
                    uint4 q2 = yp[2 * nA.z + par];
                    uint4 q3 = yp[2 * nA.w + par];
                    uint4 q4 = yp[2 * nB.x + par];
                    uint4 q5 = yp[2 * nB.y + par];
                    uint4 q6 = yp[2 * nB.z + par];
                    uint4 q7 = yp[2 * nB.w + par];
                    acc8(a, q0); acc8(a, q1); acc8(a, q2); acc8(a, q3);
                    acc8(a, q4); acc8(a, q5); acc8(a, q6); acc8(a, q7);
                }
                if (j < adeg) {
                    uint4 nA = *(const uint4*)&scsr[ofs + j];
                    uint4 q0 = yp[2 * nA.x + par];
                    uint4 q1 = yp[2 * nA.y + par];
                    uint4 q2 = yp[2 * nA.z + par];
                    uint4 q3 = yp[2 * nA.w + par];
                    acc8(a, q0); acc8(a, q1); acc8(a, q2); acc8(a, q3);
                }
            } else {
                for (; j + 8 <= adeg; j += 8) {
                    uint4 nA = *(const uint4*)(csr + s0 + j);
                    uint4 nB = *(const uint4*)(csr + s0 + j + 4);
                    uint4 q0 = yp[2 * nA.x + par];
                    uint4 q1 = yp[2 * nA.y + par];
                    uint4 q2 = yp[2 * nA.z + par];
                    uint4 q3 = yp[2 * nA.w + par];
                    uint4 q4 = yp[2 * nB.x + par];
                    uint4 q5 = yp[2 * nB.y + par];
                    uint4 q6 = yp[2 * nB.z + par];
                    uint4 q7 = yp[2 * nB.w + par];
                    acc8(a, q0); acc8(a, q1); acc8(a, q2); acc8(a, q3);
                    acc8(a, q4); acc8(a, q5); acc8(a, q6); acc8(a, q7);
                }
                if (j < adeg) {
                    uint4 nA = *(const uint4*)(csr + s0 + j);
                    uint4 q0 = yp[2 * nA.x + par];
                    uint4 q1 = yp[2 * nA.y + par];
                    uint4 q2 = yp[2 * nA.z + par];
                    uint4 q3 = yp[2 * nA.w + par];
                    acc8(a, q0); acc8(a, q1); acc8(a, q2); acc8(a, q3);
                }
            }
            float di = rsqrtf((float)(dg + 1));
            union __align__(16) Pack { bf16 hh[8]; uint4 v; } p;
            #pragma unroll
            for (int k = 0; k < 8; k++) {
                float v = a[k] * di + b[k];
                p.hh[k] = __float2bfloat16(v);
                sum[k] += v; sq[k] += v * v;
            }
            hp[2 * i + par] = p.v;
        }
    }
    #pragma unroll
    for (int k = 0; k < 8; k++) {
        float s1 = sum[k], s2 = sq[k];
        s1 += __shfl_down(s1, 32); s2 += __shfl_down(s2, 32);
        s1 += __shfl_down(s1, 16); s2 += __shfl_down(s2, 16);
        s1 += __shfl_down(s1, 8);  s2 += __shfl_down(s2, 8);
        s1 += __shfl_down(s1, 4);  s2 += __shfl_down(s2, 4);
        s1 += __shfl_down(s1, 2);  s2 += __shfl_down(s2, 2);
        if (lane < 2) { sms[ty][lane][0][k] = s1; sms[ty][lane][1][k] = s2; }
    }
    __syncthreads();
    if (t < 16) {
        int pp = t >> 3, k = t & 7;
        atomicAdd(&stat[pair * 16 + pp * 8 + k],
                  sms[0][pp][0][k] + sms[1][pp][0][k] + sms[2][pp][0][k] + sms[3][pp][0][k]);
    } else if (t >= 64 && t < 80) {
        int q = t - 64, pp = q >> 3, k = q & 7;
        atomicAdd(&stat[64 + pair * 16 + pp * 8 + k],
                  sms[0][pp][1][k] + sms[1][pp][1][k] + sms[2][pp][1][k] + sms[3][pp][1][k]);
    }
}

// ---- Pool merged: BN1+ReLU fused; reads h PAIR-MAJOR -------------------
__global__ __launch_bounds__(256) void k_poolm(
    const bf16* h_c, const float* stat_c, const float* gam_c, const float* bet_c,
    const int* batch_c, float* pooled_c, float* cnt_c, float invN_c, int N_c, int NY_c,
    const bf16* h_s, const float* stat_s, const float* gam_s, const float* bet_s,
    const int* batch_s, float* pooled_s, float* cnt_s, float invN_s, int N_s, int NY_s,
    int nblk_c) {
    const bf16* h; const float *stat, *gam, *bet; const int* batch;
    float *pooled, *cnt; float invN; int N, NY, lb, nb;
    if ((int)blockIdx.x < nblk_c) {
        lb = blockIdx.x; nb = nblk_c;
        h = h_c; stat = stat_c; gam = gam_c; bet = bet_c; batch = batch_c;
        pooled = pooled_c; cnt = cnt_c; invN = invN_c; N = N_c; NY = NY_c;
    } else {
        lb = blockIdx.x - nblk_c; nb = gridDim.x - nblk_c;
        h = h_s; stat = stat_s; gam = gam_s; bet = bet_s; batch = batch_s;
        pooled = pooled_s; cnt = cnt_s; invN = invN_s; N = N_s; NY = NY_s;
    }
    int t = threadIdx.x;
    int lane = t & 63;
    float mean = stat[lane] * invN;
    float var = stat[64 + lane] * invN - mean * mean;
    float A = gam[lane] * rsqrtf(fmaxf(var, 0.f) + EPS_);
    float B = bet[lane] - mean * A;
    size_t pbase = (size_t)(lane >> 4) * NY * 16 + (lane & 15);
    int w = (lb * 256 + t) >> 6;
    int nw = nb * 4;
    int chunk = (N + nw - 1) / nw;
    int i0 = w * chunk;
    int i1 = i0 + chunk;
    if (i1 > N) i1 = N;
    if (i0 >= N) return;
    int curg = batch[i0];
    float acc = 0.f, c = 0.f;
    for (int i = i0; i < i1; i++) {
        int g = batch[i];
        if (g != curg) {
            atomicAdd(&pooled[(size_t)curg * 64 + lane], acc);
            if (lane == 0) atomicAdd(&cnt[curg], c);
            curg = g; acc = 0.f; c = 0.f;
        }
        acc += fmaxf(b2f(h[pbase + (size_t)i * 16]) * A + B, 0.f);
        c += 1.f;
    }
    atomicAdd(&pooled[(size_t)curg * 64 + lane], acc);
    if (lane == 0) atomicAdd(&cnt[curg], c);
}

// ---- Head: 4 waves/block, one group per wave ---------------------------
__global__ __launch_bounds__(256) void k_head(const float* pooled_c, const float* cnt_c,
                                              const float* pooled_s, const float* cnt_s,
                                              const float* Wf1, const float* bf1_,
                                              const float* Wf2, const float* bf2_,
                                              float* out) {
    __shared__ float W1sm[128 * 64];
    __shared__ float W2sm[128];
    int t = threadIdx.x, lane = t & 63, w = t >> 6;
    for (int i = t; i < 128 * 64; i += 256) W1sm[i] = Wf1[i];
    if (t < 128) W2sm[t] = Wf2[t];
    __syncthreads();
    float bb1 = bf1_[lane];
    float b20 = bf2_[0];
    float b21 = bf2_[1];
    for (int g = blockIdx.x * 4 + w; g < G_; g += gridDim.x * 4) {
        float ic = 1.f / fmaxf(cnt_c[g], 1.f);
        float is = 1.f / fmaxf(cnt_s[g], 1.f);
        float hc = pooled_c[(size_t)g * 64 + lane] * ic;
        float hs = pooled_s[(size_t)g * 64 + lane] * is;
        float s = bb1;
        for (int k = 0; k < 64; k++) s += __shfl(hc, k) * W1sm[k * 64 + lane];
        for (int k = 0; k < 64; k++) s += __shfl(hs, k) * W1sm[(64 + k) * 64 + lane];
        s = fmaxf(s, 0.f);
        float p0 = s * W2sm[lane * 2 + 0];
        float p1 = s * W2sm[lane * 2 + 1];
        for (int off = 32; off > 0; off >>= 1) {
            p0 += __shfl_down(p0, off);
            p1 += __shfl_down(p1, off);
        }
        if (lane == 0) {
            out[g * 2 + 0] = p0 + b20;
            out[g * 2 + 1] = p1 + b21;
        }
    }
}

extern "C" void kernel_launch(void* const* d_in, const int* in_sizes, int n_in,
                              void* d_out, int out_size, void* d_ws, size_t ws_size,
                              hipStream_t stream) {
    float* out = (float*)d_out;

    if (n_in != 26 || in_sizes[0] != NC_ * 7 || in_sizes[1] != 2 * EC_ ||
        in_sizes[2] != NC_ || in_sizes[3] != NS_ * 7 || in_sizes[4] != 2 * ES_ ||
        in_sizes[5] != NS_ || out_size != G_ * 2) {
        k_fillout<<<(out_size + 255) / 256, 256, 0, stream>>>(out, 7777.0f, out_size);
        return;
    }
    if (ws_size < (size_t)WS_MIN_FALLBACK) {
        k_fillout<<<(out_size + 255) / 256, 256, 0, stream>>>(
            out, 1000.0f + (float)(ws_size >> 20), out_size);
        return;
    }
    const bool big = (ws_size >= (size_t)WS_BIG);

    const float* x_c     = (const float*)d_in[0];
    const int*   ei_c    = (const int*)d_in[1];
    const int*   batch_c = (const int*)d_in[2];
    const float* x_s     = (const float*)d_in[3];
    const int*   ei_s    = (const int*)d_in[4];
    const int*   batch_s = (const int*)d_in[5];
    const float* Wc0  = (const float*)d_in[6];
    const float* bc0  = (const float*)d_in[7];
    const float* gc0  = (const float*)d_in[8];
    const float* bec0 = (const float*)d_in[9];
    const float* Wc1  = (const float*)d_in[10];
    const float* bc1  = (const float*)d_in[11];
    const float* gc1  = (const float*)d_in[12];
    const float* bec1 = (const float*)d_in[13];
    const float* Ws0  = (const float*)d_in[14];
    const float* bs0  = (const float*)d_in[15];
    const float* gs0  = (const float*)d_in[16];
    const float* bes0 = (const float*)d_in[17];
    const float* Ws1  = (const float*)d_in[18];
    const float* bs1  = (const float*)d_in[19];
    const float* gs1  = (const float*)d_in[20];
    const float* bes1 = (const float*)d_in[21];
    const float* Wf1  = (const float*)d_in[22];
    const float* bf1_ = (const float*)d_in[23];
    const float* Wf2  = (const float*)d_in[24];
    const float* bf2_ = (const float*)d_in[25];

    const int NYC = NC_ + 8;
    const int NYS = NS_ + 8;

    // ---- workspace layout: bf16 buffers FIRST (aligned rows) -----------
    int* wsw = (int*)d_ws;
    size_t off = big ? (size_t)(3201024 + 3200256 + 1601536 + 1600256)
                     : (size_t)(3201024 + 3200256);
    float* stats_c  = (float*)(wsw + off); off += 256;
    float* stats_s  = (float*)(wsw + off); off += 256;
    float* pooled_c = (float*)(wsw + off); off += (size_t)G_ * 64;
    float* pooled_s = (float*)(wsw + off); off += (size_t)G_ * 64;
    float* cnt_c    = (float*)(wsw + off); off += G_;
    float* cnt_s    = (float*)(wsw + off); off += G_;
    int*   bcnt_c   = wsw + off; off += NB_C;
    int*   bcnt_s   = wsw + off; off += NB_S;
    const int zero_words = 256 + 256 + G_ * 64 * 2 + G_ * 2 + NB_C + NB_S;
    int*   bbase_c  = wsw + off; off += NB_C + 1;
    int*   bcur_c   = wsw + off; off += NB_C;
    int*   bbase_s  = wsw + off; off += NB_S + 1;
    int*   bcur_s   = wsw + off; off += NB_S;
    int*   deg_c    = wsw + off; off += NC_;
    int*   start_c  = wsw + off; off += NC_;
    int*   deg_s    = wsw + off; off += NS_;
    int*   start_s  = wsw + off; off += NS_;
    int*   csr_c    = wsw + off; off += CSR_WC;
    int*   csr_s    = wsw + off; off += CSR_WS;

    k_zero<<<512, 256, 0, stream>>>((int*)stats_c, zero_words);
    k_bhist2<<<384, 256, 0, stream>>>(ei_c + EC_, bcnt_c, ei_s + ES_, bcnt_s);
    k_bscan<<<1, 256, 0, stream>>>(bcnt_c, bbase_c, bcur_c, NB_C,
                                   bcnt_s, bbase_s, bcur_s, NB_S);

    if (big) {
        // ---- big layout: separate solvent buffers, merged pipeline ----
        bf16* h_c = (bf16*)wsw;                               // 3201024 words
        bf16* y_c = (bf16*)(wsw + 3201024);                   // 3200256 words
        bf16* h_s = (bf16*)(wsw + 3201024 + 3200256);         // 1601536 words
        bf16* y_s = (bf16*)(wsw + 3201024 + 3200256 + 1601536); // 1600256 words
        int*  ebuf_c = (int*)h_c;                 // dead before gather7m writes h_c
        int*  ebuf_s = (int*)h_c + 1600000;
        bf16* u_c = y_c;                          // dead before gemm1m writes y_c
        bf16* u_s = y_s;

        k_bin2<<<1173, 256, 0, stream>>>(ei_c, bcur_c, ebuf_c, ei_s, bcur_s, ebuf_s);
        k_build2<<<NB_C + NB_S, 256, 0, stream>>>(bbase_c, ebuf_c, x_c, u_c,
                                                  deg_c, start_c, csr_c,
                                                  bbase_s, ebuf_s, x_s, u_s,
                                                  deg_s, start_s, csr_s);
        k_gather7m<<<NB_C + NB_S, 256, 0, stream>>>(
            u_c, csr_c, start_c, deg_c, Wc0, bc0, h_c, stats_c, NC_,
            u_s, csr_s, start_s, deg_s, Ws0, bs0, h_s, stats_s, NS_, NB_C);
        k_gemm1m<<<768, 256, 0, stream>>>(
            h_c, Wc1, stats_c, gc0, bec0, deg_c, y_c, 1.0f / NC_, NC_, NYC,
            h_s, Ws1, stats_s, gs0, bes0, deg_s, y_s, 1.0f / NS_, NS_, NYS, 512);
        k_gather16p<<<1024 + 512, 256, 0, stream>>>(
            y_c, csr_c, start_c, deg_c, bc1, h_c, stats_c + 128, NC_, NYC,
            y_s, csr_s, start_s, deg_s, bs1, h_s, stats_s + 128, NS_, NYS, 1024);
        k_poolm<<<384, 256, 0, stream>>>(
            h_c, stats_c + 128, gc1, bec1, batch_c, pooled_c, cnt_c, 1.0f / NC_, NC_, NYC,
            h_s, stats_s + 128, gs1, bes1, batch_s, pooled_s, cnt_s, 1.0f / NS_, NS_, NYS, 256);
    } else {
        // ---- fallback: shared buffers, sequential branches ----
        bf16* hbuf = (bf16*)wsw;
        bf16* ybuf = (bf16*)(wsw + 3201024);
        int*  ebuf_c = (int*)hbuf;
        int*  ebuf_s = (int*)hbuf + 1600000;
        bf16* ub = ybuf;

        k_bin2<<<1173, 256, 0, stream>>>(ei_c, bcur_c, ebuf_c, ei_s, bcur_s, ebuf_s);
        k_build2<<<NB_C + NB_S, 256, 0, stream>>>(bbase_c, ebuf_c, x_c, ub,
                                                  deg_c, start_c, csr_c,
                                                  bbase_s, ebuf_s, (const float*)0, (bf16*)0,
                                                  deg_s, start_s, csr_s);
        // chromo
        k_gather7m<<<NB_C, 256, 0, stream>>>(
            ub, csr_c, start_c, deg_c, Wc0, bc0, hbuf, stats_c, NC_,
            ub, csr_c, start_c, deg_c, Wc0, bc0, hbuf, stats_c, NC_, NB_C);
        k_gemm1m<<<512, 256, 0, stream>>>(
            hbuf, Wc1, stats_c, gc0, bec0, deg_c, ybuf, 1.0f / NC_, NC_, NYC,
            hbuf, Wc1, stats_c, gc0, bec0, deg_c, ybuf, 1.0f / NC_, NC_, NYC, 512);
        k_gather16p<<<1024, 256, 0, stream>>>(
            ybuf, csr_c, start_c, deg_c, bc1, hbuf, stats_c + 128, NC_, NYC,
            ybuf, csr_c, start_c, deg_c, bc1, hbuf, stats_c + 128, NC_, NYC, 1024);
        k_poolm<<<256, 256, 0, stream>>>(
            hbuf, stats_c + 128, gc1, bec1, batch_c, pooled_c, cnt_c, 1.0f / NC_, NC_, NYC,
            hbuf, stats_c + 128, gc1, bec1, batch_c, pooled_c, cnt_c, 1.0f / NC_, NC_, NYC, 256);
        // solvent
        k_prep7<<<(NS_ + 256) / 256, 256, 0, stream>>>(x_s, deg_s, ub, NS_);
        k_gather7m<<<NB_S, 256, 0, stream>>>(
            ub, csr_s, start_s, deg_s, Ws0, bs0, hbuf, stats_s, NS_,
            ub, csr_s, start_s, deg_s, Ws0, bs0, hbuf, stats_s, NS_, NB_S);
        k_gemm1m<<<256, 256, 0, stream>>>(
            hbuf, Ws1, stats_s, gs0, bes0, deg_s, ybuf, 1.0f / NS_, NS_, NYS,
            hbuf, Ws1, stats_s, gs0, bes0, deg_s, ybuf, 1.0f / NS_, NS_, NYS, 256);
        k_gather16p<<<512, 256, 0, stream>>>(
            ybuf, csr_s, start_s, deg_s, bs1, hbuf, stats_s + 128, NS_, NYS,
            ybuf, csr_s, start_s, deg_s, bs1, hbuf, stats_s + 128, NS_, NYS, 512);
        k_poolm<<<256, 256, 0, stream>>>(
            hbuf, stats_s + 128, gs1, bes1, batch_s, pooled_s, cnt_s, 1.0f / NS_, NS_, NYS,
            hbuf, stats_s + 128, gs1, bes1, batch_s, pooled_s, cnt_s, 1.0f / NS_, NS_, NYS, 256);
    }

    k_head<<<256, 256, 0, stream>>>(pooled_c, cnt_c, pooled_s, cnt_s, Wf1, bf1_, Wf2, bf2_, out);
}

// Round 7
// 320.655 us; speedup vs baseline: 1.8958x; 1.1799x over previous
//
#include <hip/hip_runtime.h>
#include <hip/hip_bf16.h>

typedef __hip_bfloat16 bf16;
typedef __attribute__((ext_vector_type(8))) short short8;
typedef __attribute__((ext_vector_type(4))) float f32x4;

#define NC_ 100000
#define EC_ 1600000
#define NS_ 50000
#define ES_ 800000
#define G_  1024
#define EPS_ 1e-5f

#define NB_C 782
#define NB_S 391
#define NBMAX 782
#define KSL 16
#define ECAP 2560        // fixed ebuf capacity per bucket (mu=2046, +11 sigma)
#define CSRCAP 2556      // fixed csr capacity per bucket (max count+pad ~2400)
#define CSR_WC 1998792   // 782*2556
#define CSR_WS 999396    // 391*2556

#define WS_MIN_FALLBACK 39356176ull
#define WS_BIG          52163344ull

__device__ __forceinline__ float b2f(bf16 v) { return __bfloat162float(v); }

__device__ __forceinline__ unsigned short f2bfbits(float v) {
    bf16 b = __float2bfloat16(v);
    union { bf16 b; unsigned short u; } c; c.b = b; return c.u;
}

__device__ __forceinline__ void acc8(float* a, uint4 r) {
    a[0] += __uint_as_float(r.x << 16); a[1] += __uint_as_float(r.x & 0xffff0000u);
    a[2] += __uint_as_float(r.y << 16); a[3] += __uint_as_float(r.y & 0xffff0000u);
    a[4] += __uint_as_float(r.z << 16); a[5] += __uint_as_float(r.z & 0xffff0000u);
    a[6] += __uint_as_float(r.w << 16); a[7] += __uint_as_float(r.w & 0xffff0000u);
}

__global__ void DualGNN_31327491457689_kernel() {}

__global__ __launch_bounds__(256) void k_fillout(float* out, float val, int n) {
    int i = blockIdx.x * 256 + threadIdx.x;
    if (i < n) out[i] = val;
}

// ---- init: zero stats/pooled/cnt + fixed-base bucket cursors -----------
__global__ __launch_bounds__(256) void k_init(int* zp, int nzero,
                                              int* bcur_c, int* bcur_s) {
    int i = blockIdx.x * 256 + threadIdx.x;
    int stride = gridDim.x * 256;
    for (int j = i; j < nzero; j += stride) zp[j] = 0;
    if (i < NB_C) bcur_c[i] = i * ECAP;
    if (i < NB_S) bcur_s[i] = i * ECAP;
}

// ---- Phase C: bin packed edges into FIXED per-bucket regions -----------
// (no histogram/scan pass needed: bucket b owns ebuf[b*ECAP, (b+1)*ECAP))
__global__ __launch_bounds__(256) void k_bin2(const int* ei_c, int* bcur_c, int* ebuf_c,
                                              const int* ei_s, int* bcur_s, int* ebuf_s) {
    __shared__ int cnt[NBMAX];
    __shared__ int slot[NBMAX * KSL];
    int t = threadIdx.x;
    const int *src, *dst; int *bcur, *ebuf; int E, NB; int base;
    if (blockIdx.x < 391) {
        src = ei_c; dst = ei_c + EC_; bcur = bcur_c; ebuf = ebuf_c;
        E = EC_; NB = NB_C; base = blockIdx.x * 4096;
    } else {
        src = ei_s; dst = ei_s + ES_; bcur = bcur_s; ebuf = ebuf_s;
        E = ES_; NB = NB_S; base = (blockIdx.x - 391) * 4096;
    }
    if (base >= E) return;
    for (int i = t; i < NB; i += 256) cnt[i] = 0;
    __syncthreads();
    int e1 = base + 4096;
    if (e1 > E) e1 = E;
    for (int e = base + t; e < e1; e += 256) {
        int d = dst[e];
        int p = ((d & 127) << 24) | src[e];
        int b = d >> 7;
        int sl = atomicAdd(&cnt[b], 1);
        if (sl < KSL) slot[b * KSL + sl] = p;
        else { int gp = atomicAdd(&bcur[b], 1); ebuf[gp] = p; }
    }
    __syncthreads();
    for (int b = t; b < NB; b += 256) {
        int c = cnt[b];
        if (c > KSL) c = KSL;
        if (c > 0) {
            int gp = atomicAdd(&bcur[b], c);
            for (int k = 0; k < c; k++) ebuf[gp + k] = slot[b * KSL + k];
        }
    }
}

// ---- Phase D: per-bucket build + u prep (both branches) ----------------
// e0 = b*ECAP (fixed base), e1 = bcur[b] (final cursor); csr base b*CSRCAP.
__global__ __launch_bounds__(256) void k_build2(const int* bcurf_c, const int* ebuf_c,
                                                const float* x_c, bf16* u_c,
                                                int* deg_c, int* start_c, int* csr_c,
                                                const int* bcurf_s, const int* ebuf_s,
                                                const float* x_s, bf16* u_s,
                                                int* deg_s, int* start_s, int* csr_s) {
    __shared__ int lcnt[128], lofs[128], lcur[128];
    int t = threadIdx.x;
    const int* bcurf; const int* ebuf; const float* x; bf16* u;
    int* deg; int* start; int* csr; int N, b;
    if (blockIdx.x < NB_C) {
        b = blockIdx.x; bcurf = bcurf_c; ebuf = ebuf_c; x = x_c; u = u_c;
        deg = deg_c; start = start_c; csr = csr_c; N = NC_;
    } else {
        b = blockIdx.x - NB_C; bcurf = bcurf_s; ebuf = ebuf_s; x = x_s; u = u_s;
        deg = deg_s; start = start_s; csr = csr_s; N = NS_;
    }
    int e0 = b * ECAP, e1 = bcurf[b];
    int cb = b * CSRCAP;
    int n0 = b << 7;
    if (t < 128) lcnt[t] = 0;
    __syncthreads();
    for (int e = e0 + t; e < e1; e += 256)
        atomicAdd(&lcnt[((unsigned)ebuf[e]) >> 24], 1);
    __syncthreads();
    if (t < 64) {
        int c0 = lcnt[2 * t], c1 = lcnt[2 * t + 1];
        int v0 = (c0 + 3) & ~3, v1 = (c1 + 3) & ~3;
        int s = v0 + v1, incl = s;
        for (int off = 1; off < 64; off <<= 1) {
            int uu = __shfl_up(incl, off);
            if (t >= off) incl += uu;
        }
        int excl = incl - s;
        lofs[2 * t] = excl;
        lofs[2 * t + 1] = excl + v0;
    }
    __syncthreads();
    if (t < 128) {
        int node = n0 + t;
        if (node < N) {
            deg[node] = lcnt[t];
            start[node] = cb + lofs[t];
            if (x) {
                float d = rsqrtf((float)(lcnt[t] + 1));
                union __align__(16) Pack { bf16 hh[8]; uint4 v; } p;
                for (int k = 0; k < 7; k++) p.hh[k] = __float2bfloat16(x[node * 7 + k] * d);
                p.hh[7] = __float2bfloat16(0.f);
                ((uint4*)u)[node] = p.v;
            }
        }
        lcur[t] = lofs[t];
    }
    __syncthreads();
    if (t < 128) {
        int c = lcnt[t], al = (c + 3) & ~3;
        for (int k = c; k < al; k++) csr[cb + lofs[t] + k] = N;
    }
    for (int e = e0 + t; e < e1; e += 256) {
        unsigned p = (unsigned)ebuf[e];
        int dl = p >> 24;
        int pos = atomicAdd(&lcur[dl], 1);
        csr[cb + pos] = (int)(p & 0xFFFFFF);
    }
    if (b == 0 && t < 4 && u && x) ((int*)u)[N * 4 + t] = 0;   // zero sentinel row
}

// ---- u prep (fallback path only) ---------------------------------------
__global__ __launch_bounds__(256) void k_prep7(const float* x, const int* deg,
                                               bf16* u, int N) {
    int i = blockIdx.x * 256 + threadIdx.x;
    if (i > N) return;
    union __align__(16) Pack { bf16 hh[8]; uint4 v; } p;
    if (i == N) {
        p.v = (uint4){0u, 0u, 0u, 0u};
    } else {
        float d = rsqrtf((float)(deg[i] + 1));
        for (int k = 0; k < 7; k++) p.hh[k] = __float2bfloat16(x[i * 7 + k] * d);
        p.hh[7] = __float2bfloat16(0.f);
    }
    ((uint4*)u)[i] = p.v;
}

// ---- Layer 0 gather (rank-7) + fused 7x64 GEMM, 2-lane teams, merged ---
__global__ __launch_bounds__(256) void k_gather7m(
    const bf16* u_c, const int* csr_c, const int* start_c, const int* deg_c,
    const float* W_c, const float* bias_c, bf16* h_c, float* stat_c, int N_c,
    const bf16* u_s, const int* csr_s, const int* start_s, const int* deg_s,
    const float* W_s, const float* bias_s, bf16* h_s, float* stat_s, int N_s,
    int nblk_c) {
    __shared__ float Wsm[7 * 64];
    __shared__ float agg[128][9];
    __shared__ float sm[2][4][64];
    __shared__ int scsr[4096];
    const bf16* u; const int *csr, *start, *deg; const float *W, *bias;
    bf16* h; float* stat; int N, lb;
    if ((int)blockIdx.x < nblk_c) {
        lb = blockIdx.x; u = u_c; csr = csr_c; start = start_c; deg = deg_c;
        W = W_c; bias = bias_c; h = h_c; stat = stat_c; N = N_c;
    } else {
        lb = blockIdx.x - nblk_c; u = u_s; csr = csr_s; start = start_s; deg = deg_s;
        W = W_s; bias = bias_s; h = h_s; stat = stat_s; N = N_s;
    }
    int t = threadIdx.x, lane = t & 63, ty = t >> 6;
    int team = t >> 1, par = t & 1;
    for (int i = t; i < 448; i += 256) Wsm[i] = W[i];
    float b = bias[lane];
    float sum = 0.f, sq = 0.f;
    const uint4* up = (const uint4*)u;
    // stage this bucket's csr span (always <= CSRCAP <= 4096 now)
    int n0 = lb * 128;
    int last = (n0 + 127 < N) ? n0 + 127 : N - 1;
    int sbeg = start[n0];
    int span = start[last] + ((deg[last] + 3) & ~3) - sbeg;
    bool uselds = (span <= 4096);
    if (uselds) {
        for (int w = t * 4; w < span; w += 1024)
            *(int4*)&scsr[w] = *(const int4*)(csr + sbeg + w);
    }
    __syncthreads();
    int i = n0 + team;
    float a[8] = {0.f, 0.f, 0.f, 0.f, 0.f, 0.f, 0.f, 0.f};
    if (i < N) {
        int dg = deg[i], s0 = start[i];
        int adeg = (dg + 3) & ~3;
        if (par == 0) acc8(a, up[i]);            // self-loop term
        int half = ((adeg >> 1) + 3) & ~3;       // lane0: [0,half) lane1: [half,adeg)
        int jb = par ? half : 0;
        int je = par ? adeg : half;
        int j = jb;
        if (uselds) {
            int ofs = s0 - sbeg;
            for (; j + 8 <= je; j += 8) {
                uint4 nA = *(const uint4*)&scsr[ofs + j];
                uint4 nB = *(const uint4*)&scsr[ofs + j + 4];
                uint4 r0 = up[nA.x], r1 = up[nA.y], r2 = up[nA.z], r3 = up[nA.w];
                uint4 r4 = up[nB.x], r5 = up[nB.y], r6 = up[nB.z], r7 = up[nB.w];
                acc8(a, r0); acc8(a, r1); acc8(a, r2); acc8(a, r3);
                acc8(a, r4); acc8(a, r5); acc8(a, r6); acc8(a, r7);
            }
            if (j < je) {
                uint4 nA = *(const uint4*)&scsr[ofs + j];
                uint4 r0 = up[nA.x], r1 = up[nA.y], r2 = up[nA.z], r3 = up[nA.w];
                acc8(a, r0); acc8(a, r1); acc8(a, r2); acc8(a, r3);
            }
        } else {
            for (; j + 8 <= je; j += 8) {
                uint4 nA = *(const uint4*)(csr + s0 + j);
                uint4 nB = *(const uint4*)(csr + s0 + j + 4);
                uint4 r0 = up[nA.x], r1 = up[nA.y], r2 = up[nA.z], r3 = up[nA.w];
                uint4 r4 = up[nB.x], r5 = up[nB.y], r6 = up[nB.z], r7 = up[nB.w];
                acc8(a, r0); acc8(a, r1); acc8(a, r2); acc8(a, r3);
                acc8(a, r4); acc8(a, r5); acc8(a, r6); acc8(a, r7);
            }
            if (j < je) {
                uint4 nA = *(const uint4*)(csr + s0 + j);
                uint4 r0 = up[nA.x], r1 = up[nA.y], r2 = up[nA.z], r3 = up[nA.w];
                acc8(a, r0); acc8(a, r1); acc8(a, r2); acc8(a, r3);
            }
        }
    }
    #pragma unroll
    for (int k = 0; k < 7; k++) a[k] += __shfl_xor(a[k], 1);   // combine halves
    if (i < N && par == 0) {
        float di = rsqrtf((float)(deg[i] + 1));
        #pragma unroll
        for (int k = 0; k < 7; k++) agg[team][k] = a[k] * di;
    }
    __syncthreads();
    int mbase = lb * 128 + ty * 32;
    for (int mm = 0; mm < 32; mm++) {
        int node = mbase + mm;
        if (node >= N) break;
        const float* ag = agg[ty * 32 + mm];
        float s = b;
        #pragma unroll
        for (int k = 0; k < 7; k++) s += ag[k] * Wsm[k * 64 + lane];
        h[(size_t)node * 64 + lane] = __float2bfloat16(s);
        sum += s; sq += s * s;
    }
    sm[0][ty][lane] = sum;
    sm[1][ty][lane] = sq;
    __syncthreads();
    if (ty == 0) {
        atomicAdd(&stat[lane],      sm[0][0][lane] + sm[0][1][lane] + sm[0][2][lane] + sm[0][3][lane]);
        atomicAdd(&stat[64 + lane], sm[1][0][lane] + sm[1][1][lane] + sm[1][2][lane] + sm[1][3][lane]);
    }
}

// ---- Layer 1 GEMM via MFMA, merged; y PAIR-MAJOR -----------------------
__global__ __launch_bounds__(256) void k_gemm1m(
    const bf16* h_c, const float* W_c, const float* stat_c, const float* gam_c,
    const float* bet_c, const int* deg_c, bf16* y_c, float invN_c, int N_c, int NY_c,
    const bf16* h_s, const float* W_s, const float* stat_s, const float* gam_s,
    const float* bet_s, const int* deg_s, bf16* y_s, float invN_s, int N_s, int NY_s,
    int nblk_c) {
    __shared__ short Wt[64][72];
    __shared__ float AB[128];
    const bf16* h; const float *W, *stat, *gam, *bet; const int* deg;
    bf16* y; float invN; int N, NY, lb, nb;
    if ((int)blockIdx.x < nblk_c) {
        lb = blockIdx.x; nb = nblk_c;
        h = h_c; W = W_c; stat = stat_c; gam = gam_c; bet = bet_c; deg = deg_c;
        y = y_c; invN = invN_c; N = N_c; NY = NY_c;
    } else {
        lb = blockIdx.x - nblk_c; nb = gridDim.x - nblk_c;
        h = h_s; W = W_s; stat = stat_s; gam = gam_s; bet = bet_s; deg = deg_s;
        y = y_s; invN = invN_s; N = N_s; NY = NY_s;
    }
    int t = threadIdx.x, lane = t & 63, ty = t >> 6;
    for (int i = t; i < 4096; i += 256) {
        int k = i >> 6, n = i & 63;
        Wt[n][k] = (short)f2bfbits(W[i]);
    }
    if (t < 64) {
        float mean = stat[t] * invN;
        float var = stat[64 + t] * invN - mean * mean;
        float A = gam[t] * rsqrtf(fmaxf(var, 0.f) + EPS_);
        AB[t] = A;
        AB[64 + t] = bet[t] - mean * A;
    }
    if (lb == 0 && t < 64) {     // zero sentinel row N of each pair
        int pr = t >> 4, cl = t & 15;
        y[((size_t)pr * NY + N) * 16 + cl] = __float2bfloat16(0.f);
    }
    __syncthreads();
    int quad = lane >> 4, l16 = lane & 15;
    short8 Bf[2][4];
    #pragma unroll
    for (int kt = 0; kt < 2; kt++)
        #pragma unroll
        for (int nt = 0; nt < 4; nt++) {
            int n = nt * 16 + l16, k0 = kt * 32 + quad * 8;
            Bf[kt][nt] = *(const short8*)&Wt[n][k0];
        }
    int ntile = (N + 63) >> 6;
    for (int tile = lb * 4 + ty; tile < ntile; tile += nb * 4) {
        int base = tile << 6;
        f32x4 acc[4][4];
        #pragma unroll
        for (int a = 0; a < 4; a++)
            #pragma unroll
            for (int b = 0; b < 4; b++) acc[a][b] = (f32x4){0.f, 0.f, 0.f, 0.f};
        #pragma unroll
        for (int kt = 0; kt < 2; kt++) {
            int k0 = kt * 32 + quad * 8;
            float Ak[8], Bk[8];
            #pragma unroll
            for (int j = 0; j < 8; j++) { Ak[j] = AB[k0 + j]; Bk[j] = AB[64 + k0 + j]; }
            #pragma unroll
            for (int mt = 0; mt < 4; mt++) {
                int node = base + mt * 16 + l16;     // tail overread: h padded
                uint4 raw = *(const uint4*)(h + (size_t)node * 64 + k0);
                unsigned rr[4] = {raw.x, raw.y, raw.z, raw.w};
                short8 af;
                #pragma unroll
                for (int j = 0; j < 8; j++) {
                    unsigned bits = (j & 1) ? (rr[j >> 1] & 0xffff0000u)
                                            : (rr[j >> 1] << 16);
                    float v = __uint_as_float(bits);
                    v = fmaxf(v * Ak[j] + Bk[j], 0.f);
                    af[j] = (short)f2bfbits(v);
                }
                #pragma unroll
                for (int nt = 0; nt < 4; nt++)
                    acc[mt][nt] = __builtin_amdgcn_mfma_f32_16x16x32_bf16(
                        af, Bf[kt][nt], acc[mt][nt], 0, 0, 0);
            }
        }
        #pragma unroll
        for (int mt = 0; mt < 4; mt++)
            #pragma unroll
            for (int r = 0; r < 4; r++) {
                int node = base + mt * 16 + quad * 4 + r;
                if (node < N) {
                    float dinv = rsqrtf((float)(deg[node] + 1));
                    #pragma unroll
                    for (int nt = 0; nt < 4; nt++)
                        y[((size_t)nt * NY + node) * 16 + l16] =
                            __float2bfloat16(acc[mt][nt][r] * dinv);
                }
            }
    }
}

// ---- Layer-1 gather: PAIR-MAJOR, 2-lane teams, LDS-staged csr ----------
__global__ __launch_bounds__(256) void k_gather16p(
    const bf16* y_c, const int* csr_c, const int* start_c, const int* deg_c,
    const float* bias_c, bf16* h_c, float* stat_c, int N_c, int NY_c,
    const bf16* y_s, const int* csr_s, const int* start_s, const int* deg_s,
    const float* bias_s, bf16* h_s, float* stat_s, int N_s, int NY_s,
    int nblk_c) {
    __shared__ float sms[4][2][2][8];
    __shared__ int scsr[4096];
    const bf16* y; const int *csr, *start, *deg; const float* bias;
    bf16* h; float* stat; int N, NY, lb, nb;
    if ((int)blockIdx.x < nblk_c) {
        lb = blockIdx.x; nb = nblk_c;
        y = y_c; csr = csr_c; start = start_c; deg = deg_c; bias = bias_c;
        h = h_c; stat = stat_c; N = N_c; NY = NY_c;
    } else {
        lb = blockIdx.x - nblk_c; nb = gridDim.x - nblk_c;
        y = y_s; csr = csr_s; start = start_s; deg = deg_s; bias = bias_s;
        h = h_s; stat = stat_s; N = N_s; NY = NY_s;
    }
    int t = threadIdx.x, lane = t & 63, ty = t >> 6;
    int team = lane >> 1, par = lane & 1;
    int pair = lb & 3;
    int grp = lb >> 2;
    int ngrp = nb >> 2;
    const uint4* yp = (const uint4*)y + (size_t)pair * NY * 2;
    uint4* hp = (uint4*)h + (size_t)pair * NY * 2;
    float b[8];
    #pragma unroll
    for (int k = 0; k < 8; k++) b[k] = bias[pair * 16 + par * 8 + k];
    float sum[8], sq[8];
    #pragma unroll
    for (int k = 0; k < 8; k++) { sum[k] = 0.f; sq[k] = 0.f; }
    for (int c0 = grp * 128; c0 < N; c0 += ngrp * 128) {
        int last = (c0 + 127 < N) ? c0 + 127 : N - 1;
        int sbeg = start[c0];
        int span = start[last] + ((deg[last] + 3) & ~3) - sbeg;
        bool uselds = (span <= 4096);
        if (uselds) {
            __syncthreads();                       // protect prior sweep's reads
            for (int w = t * 4; w < span; w += 1024)
                *(int4*)&scsr[w] = *(const int4*)(csr + sbeg + w);
            __syncthreads();
        }
        int i = c0 + ty * 32 + team;
        if (i <= last) {
            int dg = deg[i], s0 = start[i];
            int adeg = (dg + 3) & ~3;
            float a[8];
            #pragma unroll
            for (int k = 0; k < 8; k++) a[k] = 0.f;
            acc8(a, yp[2 * i + par]);                // self-loop
            int j = 0;
            if (uselds) {
                int ofs = s0 - sbeg;
                for (; j + 8 <= adeg; j += 8) {
                    uint4 nA = *(const uint4*)&scsr[ofs + j];
                    uint4 nB = *(const uint4*)&scsr[ofs + j + 4];
                    uint4 q0 = yp[2 * nA.x + par];
                    uint4 q1 = yp[2 * nA.y + par];
                    uint4 q2 = yp[2 * nA.z + par];
                    uint4 q3 = yp[2 * nA.w + par];
                    uint4 q4 = yp[2 * nB.x + par];
                    uint4 q5 = yp[2 * nB.y + par];
                    uint4 q6 = yp[2 * nB.z + par];
                    uint4 q7 = yp[2 * nB.w + par];
                    acc8(a, q0); acc8(a, q1); acc8(a, q2); acc8(a, q3);
                    acc8(a, q4); acc8(a, q5); acc8(a, q6); acc8(a, q7);
                }
                if (j < adeg) {
                    uint4 nA = *(const uint4*)&scsr[ofs + j];
                    uint4 q0 = yp[2 * nA.x + par];
                    uint4 q1 = yp[2 * nA.y + par];
                    uint4 q2 = yp[2 * nA.z + par];
                    uint4 q3 = yp[2 * nA.w + par];
                    acc8(a, q0); acc8(a, q1); acc8(a, q2); acc8(a, q3);
                }
            } else {
                for (; j + 8 <= adeg; j += 8) {
                    uint4 nA = *(const uint4*)(csr + s0 + j);
                    uint4 nB = *(const uint4*)(csr + s0 + j + 4);
                    uint4 q0 = yp[2 * nA.x + par];
                    uint4 q1 = yp[2 * nA.y + par];
                    uint4 q2 = yp[2 * nA.z + par];
                    uint4 q3 = yp[2 * nA.w + par];
                    uint4 q4 = yp[2 * nB.x + par];
                    uint4 q5 = yp[2 * nB.y + par];
                    uint4 q6 = yp[2 * nB.z + par];
                    uint4 q7 = yp[2 * nB.w + par];
                    acc8(a, q0); acc8(a, q1); acc8(a, q2); acc8(a, q3);
                    acc8(a, q4); acc8(a, q5); acc8(a, q6); acc8(a, q7);
                }
                if (j < adeg) {
                    uint4 nA = *(const uint4*)(csr + s0 + j);
                    uint4 q0 = yp[2 * nA.x + par];
                    uint4 q1 = yp[2 * nA.y + par];
                    uint4 q2 = yp[2 * nA.z + par];
                    uint4 q3 = yp[2 * nA.w + par];
                    acc8(a, q0); acc8(a, q1); acc8(a, q2); acc8(a, q3);
                }
            }
            float di = rsqrtf((float)(dg + 1));
            union __align__(16) Pack { bf16 hh[8]; uint4 v; } p;
            #pragma unroll
            for (int k = 0; k < 8; k++) {
                float v = a[k] * di + b[k];
                p.hh[k] = __float2bfloat16(v);
                sum[k] += v; sq[k] += v * v;
            }
            hp[2 * i + par] = p.v;
        }
    }
    #pragma unroll
    for (int k = 0; k < 8; k++) {
        float s1 = sum[k], s2 = sq[k];
        s1 += __shfl_down(s1, 32); s2 += __shfl_down(s2, 32);
        s1 += __shfl_down(s1, 16); s2 += __shfl_down(s2, 16);
        s1 += __shfl_down(s1, 8);  s2 += __shfl_down(s2, 8);
        s1 += __shfl_down(s1, 4);  s2 += __shfl_down(s2, 4);
        s1 += __shfl_down(s1, 2);  s2 += __shfl_down(s2, 2);
        if (lane < 2) { sms[ty][lane][0][k] = s1; sms[ty][lane][1][k] = s2; }
    }
    __syncthreads();
    if (t < 16) {
        int pp = t >> 3, k = t & 7;
        atomicAdd(&stat[pair * 16 + pp * 8 + k],
                  sms[0][pp][0][k] + sms[1][pp][0][k] + sms[2][pp][0][k] + sms[3][pp][0][k]);
    } else if (t >= 64 && t < 80) {
        int q = t - 64, pp = q >> 3, k = q & 7;
        atomicAdd(&stat[64 + pair * 16 + pp * 8 + k],
                  sms[0][pp][1][k] + sms[1][pp][1][k] + sms[2][pp][1][k] + sms[3][pp][1][k]);
    }
}

// ---- Pool merged: BN1+ReLU fused; reads h PAIR-MAJOR -------------------
__global__ __launch_bounds__(256) void k_poolm(
    const bf16* h_c, const float* stat_c, const float* gam_c, const float* bet_c,
    const int* batch_c, float* pooled_c, float* cnt_c, float invN_c, int N_c, int NY_c,
    const bf16* h_s, const float* stat_s, const float* gam_s, const float* bet_s,
    const int* batch_s, float* pooled_s, float* cnt_s, float invN_s, int N_s, int NY_s,
    int nblk_c) {
    const bf16* h; const float *stat, *gam, *bet; const int* batch;
    float *pooled, *cnt; float invN; int N, NY, lb, nb;
    if ((int)blockIdx.x < nblk_c) {
        lb = blockIdx.x; nb = nblk_c;
        h = h_c; stat = stat_c; gam = gam_c; bet = bet_c; batch = batch_c;
        pooled = pooled_c; cnt = cnt_c; invN = invN_c; N = N_c; NY = NY_c;
    } else {
        lb = blockIdx.x - nblk_c; nb = gridDim.x - nblk_c;
        h = h_s; stat = stat_s; gam = gam_s; bet = bet_s; batch = batch_s;
        pooled = pooled_s; cnt = cnt_s; invN = invN_s; N = N_s; NY = NY_s;
    }
    int t = threadIdx.x;
    int lane = t & 63;
    float mean = stat[lane] * invN;
    float var = stat[64 + lane] * invN - mean * mean;
    float A = gam[lane] * rsqrtf(fmaxf(var, 0.f) + EPS_);
    float B = bet[lane] - mean * A;
    size_t pbase = (size_t)(lane >> 4) * NY * 16 + (lane & 15);
    int w = (lb * 256 + t) >> 6;
    int nw = nb * 4;
    int chunk = (N + nw - 1) / nw;
    int i0 = w * chunk;
    int i1 = i0 + chunk;
    if (i1 > N) i1 = N;
    if (i0 >= N) return;
    int curg = batch[i0];
    float acc = 0.f, c = 0.f;
    for (int i = i0; i < i1; i++) {
        int g = batch[i];
        if (g != curg) {
            atomicAdd(&pooled[(size_t)curg * 64 + lane], acc);
            if (lane == 0) atomicAdd(&cnt[curg], c);
            curg = g; acc = 0.f; c = 0.f;
        }
        acc += fmaxf(b2f(h[pbase + (size_t)i * 16]) * A + B, 0.f);
        c += 1.f;
    }
    atomicAdd(&pooled[(size_t)curg * 64 + lane], acc);
    if (lane == 0) atomicAdd(&cnt[curg], c);
}

// ---- Head: 4 waves/block, one group per wave ---------------------------
__global__ __launch_bounds__(256) void k_head(const float* pooled_c, const float* cnt_c,
                                              const float* pooled_s, const float* cnt_s,
                                              const float* Wf1, const float* bf1_,
                                              const float* Wf2, const float* bf2_,
                                              float* out) {
    __shared__ float W1sm[128 * 64];
    __shared__ float W2sm[128];
    int t = threadIdx.x, lane = t & 63, w = t >> 6;
    for (int i = t; i < 128 * 64; i += 256) W1sm[i] = Wf1[i];
    if (t < 128) W2sm[t] = Wf2[t];
    __syncthreads();
    float bb1 = bf1_[lane];
    float b20 = bf2_[0];
    float b21 = bf2_[1];
    for (int g = blockIdx.x * 4 + w; g < G_; g += gridDim.x * 4) {
        float ic = 1.f / fmaxf(cnt_c[g], 1.f);
        float is = 1.f / fmaxf(cnt_s[g], 1.f);
        float hc = pooled_c[(size_t)g * 64 + lane] * ic;
        float hs = pooled_s[(size_t)g * 64 + lane] * is;
        float s = bb1;
        for (int k = 0; k < 64; k++) s += __shfl(hc, k) * W1sm[k * 64 + lane];
        for (int k = 0; k < 64; k++) s += __shfl(hs, k) * W1sm[(64 + k) * 64 + lane];
        s = fmaxf(s, 0.f);
        float p0 = s * W2sm[lane * 2 + 0];
        float p1 = s * W2sm[lane * 2 + 1];
        for (int off = 32; off > 0; off >>= 1) {
            p0 += __shfl_down(p0, off);
            p1 += __shfl_down(p1, off);
        }
        if (lane == 0) {
            out[g * 2 + 0] = p0 + b20;
            out[g * 2 + 1] = p1 + b21;
        }
    }
}

extern "C" void kernel_launch(void* const* d_in, const int* in_sizes, int n_in,
                              void* d_out, int out_size, void* d_ws, size_t ws_size,
                              hipStream_t stream) {
    float* out = (float*)d_out;

    if (n_in != 26 || in_sizes[0] != NC_ * 7 || in_sizes[1] != 2 * EC_ ||
        in_sizes[2] != NC_ || in_sizes[3] != NS_ * 7 || in_sizes[4] != 2 * ES_ ||
        in_sizes[5] != NS_ || out_size != G_ * 2) {
        k_fillout<<<(out_size + 255) / 256, 256, 0, stream>>>(out, 7777.0f, out_size);
        return;
    }
    if (ws_size < (size_t)WS_MIN_FALLBACK) {
        k_fillout<<<(out_size + 255) / 256, 256, 0, stream>>>(
            out, 1000.0f + (float)(ws_size >> 20), out_size);
        return;
    }
    const bool big = (ws_size >= (size_t)WS_BIG);

    const float* x_c     = (const float*)d_in[0];
    const int*   ei_c    = (const int*)d_in[1];
    const int*   batch_c = (const int*)d_in[2];
    const float* x_s     = (const float*)d_in[3];
    const int*   ei_s    = (const int*)d_in[4];
    const int*   batch_s = (const int*)d_in[5];
    const float* Wc0  = (const float*)d_in[6];
    const float* bc0  = (const float*)d_in[7];
    const float* gc0  = (const float*)d_in[8];
    const float* bec0 = (const float*)d_in[9];
    const float* Wc1  = (const float*)d_in[10];
    const float* bc1  = (const float*)d_in[11];
    const float* gc1  = (const float*)d_in[12];
    const float* bec1 = (const float*)d_in[13];
    const float* Ws0  = (const float*)d_in[14];
    const float* bs0  = (const float*)d_in[15];
    const float* gs0  = (const float*)d_in[16];
    const float* bes0 = (const float*)d_in[17];
    const float* Ws1  = (const float*)d_in[18];
    const float* bs1  = (const float*)d_in[19];
    const float* gs1  = (const float*)d_in[20];
    const float* bes1 = (const float*)d_in[21];
    const float* Wf1  = (const float*)d_in[22];
    const float* bf1_ = (const float*)d_in[23];
    const float* Wf2  = (const float*)d_in[24];
    const float* bf2_ = (const float*)d_in[25];

    const int NYC = NC_ + 8;
    const int NYS = NS_ + 8;

    // ---- workspace layout: bf16 buffers FIRST (aligned rows) -----------
    int* wsw = (int*)d_ws;
    size_t off = big ? (size_t)(3201024 + 3200256 + 1601536 + 1600256)
                     : (size_t)(3201024 + 3200256);
    float* stats_c  = (float*)(wsw + off); off += 256;
    float* stats_s  = (float*)(wsw + off); off += 256;
    float* pooled_c = (float*)(wsw + off); off += (size_t)G_ * 64;
    float* pooled_s = (float*)(wsw + off); off += (size_t)G_ * 64;
    float* cnt_c    = (float*)(wsw + off); off += G_;
    float* cnt_s    = (float*)(wsw + off); off += G_;
    const int zero_words = 256 + 256 + G_ * 64 * 2 + G_ * 2;
    int*   bcur_c   = wsw + off; off += NB_C;
    int*   bcur_s   = wsw + off; off += NB_S;
    int*   deg_c    = wsw + off; off += NC_;
    int*   start_c  = wsw + off; off += NC_;
    int*   deg_s    = wsw + off; off += NS_;
    int*   start_s  = wsw + off; off += NS_;
    int*   csr_c    = wsw + off; off += CSR_WC;
    int*   csr_s    = wsw + off; off += CSR_WS;

    k_init<<<512, 256, 0, stream>>>((int*)stats_c, zero_words, bcur_c, bcur_s);

    if (big) {
        // ---- big layout: separate solvent buffers, merged pipeline ----
        bf16* h_c = (bf16*)wsw;                               // 3201024 words
        bf16* y_c = (bf16*)(wsw + 3201024);                   // 3200256 words
        bf16* h_s = (bf16*)(wsw + 3201024 + 3200256);         // 1601536 words
        bf16* y_s = (bf16*)(wsw + 3201024 + 3200256 + 1601536); // 1600256 words
        int*  ebuf_c = (int*)h_c;                 // 782*ECAP = 2001920 words
        int*  ebuf_s = (int*)h_c + NB_C * ECAP;   // 391*ECAP = 1000960 words
        bf16* u_c = y_c;                          // dead before gemm1m writes y_c
        bf16* u_s = y_s;

        k_bin2<<<587, 256, 0, stream>>>(ei_c, bcur_c, ebuf_c, ei_s, bcur_s, ebuf_s);
        k_build2<<<NB_C + NB_S, 256, 0, stream>>>(bcur_c, ebuf_c, x_c, u_c,
                                                  deg_c, start_c, csr_c,
                                                  bcur_s, ebuf_s, x_s, u_s,
                                                  deg_s, start_s, csr_s);
        k_gather7m<<<NB_C + NB_S, 256, 0, stream>>>(
            u_c, csr_c, start_c, deg_c, Wc0, bc0, h_c, stats_c, NC_,
            u_s, csr_s, start_s, deg_s, Ws0, bs0, h_s, stats_s, NS_, NB_C);
        k_gemm1m<<<768, 256, 0, stream>>>(
            h_c, Wc1, stats_c, gc0, bec0, deg_c, y_c, 1.0f / NC_, NC_, NYC,
            h_s, Ws1, stats_s, gs0, bes0, deg_s, y_s, 1.0f / NS_, NS_, NYS, 512);
        k_gather16p<<<1024 + 512, 256, 0, stream>>>(
            y_c, csr_c, start_c, deg_c, bc1, h_c, stats_c + 128, NC_, NYC,
            y_s, csr_s, start_s, deg_s, bs1, h_s, stats_s + 128, NS_, NYS, 1024);
        k_poolm<<<384, 256, 0, stream>>>(
            h_c, stats_c + 128, gc1, bec1, batch_c, pooled_c, cnt_c, 1.0f / NC_, NC_, NYC,
            h_s, stats_s + 128, gs1, bes1, batch_s, pooled_s, cnt_s, 1.0f / NS_, NS_, NYS, 256);
    } else {
        // ---- fallback: shared buffers, sequential branches ----
        bf16* hbuf = (bf16*)wsw;
        bf16* ybuf = (bf16*)(wsw + 3201024);
        int*  ebuf_c = (int*)hbuf;
        int*  ebuf_s = (int*)hbuf + NB_C * ECAP;
        bf16* ub = ybuf;

        k_bin2<<<587, 256, 0, stream>>>(ei_c, bcur_c, ebuf_c, ei_s, bcur_s, ebuf_s);
        k_build2<<<NB_C + NB_S, 256, 0, stream>>>(bcur_c, ebuf_c, x_c, ub,
                                                  deg_c, start_c, csr_c,
                                                  bcur_s, ebuf_s, (const float*)0, (bf16*)0,
                                                  deg_s, start_s, csr_s);
        // chromo
        k_gather7m<<<NB_C, 256, 0, stream>>>(
            ub, csr_c, start_c, deg_c, Wc0, bc0, hbuf, stats_c, NC_,
            ub, csr_c, start_c, deg_c, Wc0, bc0, hbuf, stats_c, NC_, NB_C);
        k_gemm1m<<<512, 256, 0, stream>>>(
            hbuf, Wc1, stats_c, gc0, bec0, deg_c, ybuf, 1.0f / NC_, NC_, NYC,
            hbuf, Wc1, stats_c, gc0, bec0, deg_c, ybuf, 1.0f / NC_, NC_, NYC, 512);
        k_gather16p<<<1024, 256, 0, stream>>>(
            ybuf, csr_c, start_c, deg_c, bc1, hbuf, stats_c + 128, NC_, NYC,
            ybuf, csr_c, start_c, deg_c, bc1, hbuf, stats_c + 128, NC_, NYC, 1024);
        k_poolm<<<256, 256, 0, stream>>>(
            hbuf, stats_c + 128, gc1, bec1, batch_c, pooled_c, cnt_c, 1.0f / NC_, NC_, NYC,
            hbuf, stats_c + 128, gc1, bec1, batch_c, pooled_c, cnt_c, 1.0f / NC_, NC_, NYC, 256);
        // solvent
        k_prep7<<<(NS_ + 256) / 256, 256, 0, stream>>>(x_s, deg_s, ub, NS_);
        k_gather7m<<<NB_S, 256, 0, stream>>>(
            ub, csr_s, start_s, deg_s, Ws0, bs0, hbuf, stats_s, NS_,
            ub, csr_s, start_s, deg_s, Ws0, bs0, hbuf, stats_s, NS_, NB_S);
        k_gemm1m<<<256, 256, 0, stream>>>(
            hbuf, Ws1, stats_s, gs0, bes0, deg_s, ybuf, 1.0f / NS_, NS_, NYS,
            hbuf, Ws1, stats_s, gs0, bes0, deg_s, ybuf, 1.0f / NS_, NS_, NYS, 256);
        k_gather16p<<<512, 256, 0, stream>>>(
            ybuf, csr_s, start_s, deg_s, bs1, hbuf, stats_s + 128, NS_, NYS,
            ybuf, csr_s, start_s, deg_s, bs1, hbuf, stats_s + 128, NS_, NYS, 512);
        k_poolm<<<256, 256, 0, stream>>>(
            hbuf, stats_s + 128, gs1, bes1, batch_s, pooled_s, cnt_s, 1.0f / NS_, NS_, NYS,
            hbuf, stats_s + 128, gs1, bes1, batch_s, pooled_s, cnt_s, 1.0f / NS_, NS_, NYS, 256);
    }

    k_head<<<256, 256, 0, stream>>>(pooled_c, cnt_c, pooled_s, cnt_s, Wf1, bf1_, Wf2, bf2_, out);
}